// Round 1
// baseline (887.000 us; speedup 1.0000x reference)
//
#include <hip/hip_runtime.h>
#include <stdint.h>

// ---------------------------------------------------------------------------
// D-ETM decoder: alphas = mu + eps*exp(0.5*ls); KL(alphas prior); 
// beta = softmax(alphas @ W^T, axis=V); out = [beta(125M f32), kl(1 f32)]
//
// GEMM strategy: fp32 -> bf16 hi/lo split, single bf16 MFMA GEMM with
// K = 3*256 = 768:  A' = [Ah | Ah | Al],  W' = [Wh | Wl | Wh]
// => logits = Ah*Wh + Ah*Wl + Al*Wh  (error ~2^-16 per term, way under thr).
//
// ws layout (needs ~88.9 MB):
//   Wp  [50048][768] bf16   off 0
//   Ap  [2560][768]  bf16   off 76,873,728
//   pm  [391][2560]  f32    off 80,805,888   per-(vtile,row) partial max
//   ps  [391][2560]  f32    off 84,809,728   per-(vtile,row) partial sumexp
//   Ms  [2560]       f32    off 88,813,568
//   Ss  [2560]       f32    off 88,823,808
//   bs  [2500]       f32    off 88,834,048   per-block KL partial sums
// ---------------------------------------------------------------------------

typedef __bf16 bf16x8 __attribute__((ext_vector_type(8)));
typedef float f32x4 __attribute__((ext_vector_type(4)));

#define TT 50
#define KTOP 50
#define RHO 256
#define VOCAB 50000
#define NROWS 2500
#define MPAD 2560
#define KS 768
#define BM 128
#define BN 128
#define BKS 64
#define NTN 391   // ceil(50000/128)
#define LOG_DELTA (-5.29831736f)

#define WP_OFF 0L
#define AP_OFF 76873728L
#define PM_OFF 80805888L
#define PS_OFF 84809728L
#define MS_OFF 88813568L
#define SS_OFF 88823808L
#define BS_OFF 88834048L

#define AS1(p) ((__attribute__((address_space(1))) void*)(uintptr_t)(p))
#define AS3(p) ((__attribute__((address_space(3))) void*)(p))

// ---- K1: alphas, bf16 split of A', KL per-block partial sums --------------
__global__ __launch_bounds__(256) void k1_alphas_kl(
    const float* __restrict__ mu, const float* __restrict__ ls,
    const float* __restrict__ eps, __bf16* __restrict__ Ap,
    float* __restrict__ blksum)
{
    int b = blockIdx.x;          // row = t*50 + k, 0..2499
    int r = threadIdx.x;         // 0..255
    int t = b / KTOP;
    int k = b - t * KTOP;
    long iMu = ((long)k * TT + t) * RHO + r;     // mu_q_alpha[k][t][r]
    long iEp = ((long)t * KTOP + k) * RHO + r;   // eps[t][k][r]
    float m = mu[iMu], l = ls[iMu], e = eps[iEp];
    float alpha = fmaf(e, __expf(0.5f * l), m);

    __bf16 ah = (__bf16)alpha;
    float ahf = (float)ah;
    __bf16 al = (__bf16)(alpha - ahf);
    long ro = (long)b * KS;
    Ap[ro + r] = ah;
    Ap[ro + RHO + r] = ah;
    Ap[ro + 2 * RHO + r] = al;

    // KL term (t==0 prior N(0,1); t>0 prior N(alphas[t-1], delta))
    float p_mu = 0.0f, p_ls = 0.0f, denom = 1.0f + 1e-6f;
    if (t > 0) {
        float m0 = mu[iMu - RHO];                 // (k, t-1, r)
        float l0 = ls[iMu - RHO];
        float e0 = eps[iEp - (long)KTOP * RHO];   // (t-1, k, r)
        p_mu = fmaf(e0, __expf(0.5f * l0), m0);
        p_ls = LOG_DELTA;
        denom = 0.005f + 1e-6f;
    }
    float sq = __expf(l);
    float d = m - p_mu;
    float term = (sq + d * d) / denom - 1.0f + p_ls - l;

    __shared__ float sred[256];
    sred[r] = term;
    __syncthreads();
    for (int s = 128; s > 0; s >>= 1) {
        if (r < s) sred[r] += sred[r + s];
        __syncthreads();
    }
    if (r == 0) blksum[b] = sred[0];
}

// ---- K1b: W bf16 split ----------------------------------------------------
__global__ __launch_bounds__(256) void k1b_wsplit(
    const float* __restrict__ W, __bf16* __restrict__ Wp)
{
    long v = blockIdx.x;         // 0..49999
    int r = threadIdx.x;
    float w = W[v * RHO + r];
    __bf16 wh = (__bf16)w;
    float whf = (float)wh;
    __bf16 wl = (__bf16)(w - whf);
    long o = v * KS;
    Wp[o + r] = wh;
    Wp[o + RHO + r] = wl;
    Wp[o + 2 * RHO + r] = wh;
}

// ---- K2: bf16 MFMA GEMM (M=2560, N=50048, K=768) + logit store + partials -
__global__ __launch_bounds__(256) void k2_gemm(
    const __bf16* __restrict__ Ap, const __bf16* __restrict__ Wp,
    float* __restrict__ logits, float* __restrict__ pm, float* __restrict__ ps)
{
    __shared__ alignas(16) __bf16 As[BM * BKS];
    __shared__ alignas(16) __bf16 Ws[BN * BKS];
    __shared__ float red_m[2][BM];
    __shared__ float red_s[2][BM];

    const int tid = threadIdx.x;
    const int wave = tid >> 6;
    const int lane = tid & 63;
    const int tm = blockIdx.x;   // 0..19
    const int tn = blockIdx.y;   // 0..390
    const int wr = wave >> 1;    // 0..1 row half
    const int wc = wave & 1;     // 0..1 col half
    const int lhi = lane >> 4;   // 0..3
    const int llo = lane & 15;

    f32x4 acc[4][4];
#pragma unroll
    for (int m = 0; m < 4; ++m)
#pragma unroll
        for (int n = 0; n < 4; ++n)
#pragma unroll
            for (int i = 0; i < 4; ++i) acc[m][n][i] = 0.0f;

    const long arow0 = (long)tm * BM;
    const long wrow0 = (long)tn * BN;

    for (int kt = 0; kt < KS / BKS; ++kt) {
        // stage A tile and W tile: 16 segments of 8 rows each, 4 per wave
#pragma unroll
        for (int i = 0; i < 4; ++i) {
            int seg = wave * 4 + i;                 // 0..15
            int row = seg * 8 + (lane >> 3);        // 0..127
            int col = (lane & 7) * 8;               // bf16 col within BK
            const __bf16* srcA = Ap + (arow0 + row) * KS + kt * BKS + col;
            __builtin_amdgcn_global_load_lds(AS1(srcA), AS3(&As[seg * 8 * BKS]), 16, 0, 0);
            const __bf16* srcW = Wp + (wrow0 + row) * KS + kt * BKS + col;
            __builtin_amdgcn_global_load_lds(AS1(srcW), AS3(&Ws[seg * 8 * BKS]), 16, 0, 0);
        }
        __syncthreads();
#pragma unroll
        for (int kk = 0; kk < BKS / 32; ++kk) {
            bf16x8 af[4], bfr[4];
#pragma unroll
            for (int m = 0; m < 4; ++m) {
                int r = wr * 64 + m * 16 + llo;
                af[m] = *(const bf16x8*)&As[r * BKS + kk * 32 + lhi * 8];
            }
#pragma unroll
            for (int n = 0; n < 4; ++n) {
                int r = wc * 64 + n * 16 + llo;
                bfr[n] = *(const bf16x8*)&Ws[r * BKS + kk * 32 + lhi * 8];
            }
#pragma unroll
            for (int m = 0; m < 4; ++m)
#pragma unroll
                for (int n = 0; n < 4; ++n)
                    acc[m][n] = __builtin_amdgcn_mfma_f32_16x16x32_bf16(
                        af[m], bfr[n], acc[m][n], 0, 0, 0);
        }
        __syncthreads();
    }

    // ---- epilogue: store raw logits ----
#pragma unroll
    for (int m = 0; m < 4; ++m) {
#pragma unroll
        for (int i = 0; i < 4; ++i) {
            long rg = arow0 + wr * 64 + m * 16 + lhi * 4 + i;
            if (rg < NROWS) {
#pragma unroll
                for (int n = 0; n < 4; ++n) {
                    int cg = tn * BN + wc * 64 + n * 16 + llo;
                    if (cg < VOCAB) logits[rg * VOCAB + cg] = acc[m][n][i];
                }
            }
        }
    }

    // ---- per-row (max, sumexp) partials over this 128-col tile ----
#pragma unroll
    for (int m = 0; m < 4; ++m) {
#pragma unroll
        for (int i = 0; i < 4; ++i) {
            float mx = -1e30f;
#pragma unroll
            for (int n = 0; n < 4; ++n) {
                int cg = tn * BN + wc * 64 + n * 16 + llo;
                if (cg < VOCAB) mx = fmaxf(mx, acc[m][n][i]);
            }
#pragma unroll
            for (int dm = 1; dm < 16; dm <<= 1) mx = fmaxf(mx, __shfl_xor(mx, dm));
            float sm = 0.0f;
#pragma unroll
            for (int n = 0; n < 4; ++n) {
                int cg = tn * BN + wc * 64 + n * 16 + llo;
                if (cg < VOCAB) sm += __expf(acc[m][n][i] - mx);
            }
#pragma unroll
            for (int dm = 1; dm < 16; dm <<= 1) sm += __shfl_xor(sm, dm);
            if (llo == 0) {
                int rl = wr * 64 + m * 16 + lhi * 4 + i;
                red_m[wc][rl] = mx;
                red_s[wc][rl] = sm;
            }
        }
    }
    __syncthreads();
    if (tid < BM) {
        float m0 = red_m[0][tid], m1 = red_m[1][tid];
        float M = fmaxf(m0, m1);
        float S = red_s[0][tid] * __expf(m0 - M) + red_s[1][tid] * __expf(m1 - M);
        long idx = (long)tn * MPAD + tm * BM + tid;
        pm[idx] = M;
        ps[idx] = S;
    }
}

// ---- K3: combine per-tile partials -> per-row (M, S) ----------------------
__global__ __launch_bounds__(256) void k3_rowstats(
    const float* __restrict__ pm, const float* __restrict__ ps,
    float* __restrict__ Ms, float* __restrict__ Ss)
{
    int row = blockIdx.x * 256 + threadIdx.x;
    if (row >= NROWS) return;
    float M = -1e30f;
    for (int j = 0; j < NTN; ++j) M = fmaxf(M, pm[(long)j * MPAD + row]);
    float S = 0.0f;
    for (int j = 0; j < NTN; ++j)
        S += ps[(long)j * MPAD + row] * __expf(pm[(long)j * MPAD + row] - M);
    Ms[row] = M;
    Ss[row] = S;
}

// ---- K4: beta = exp(logit - M) / S, in-place over d_out -------------------
__global__ __launch_bounds__(256) void k4_scale(
    float* __restrict__ out, const float* __restrict__ Ms,
    const float* __restrict__ Ss)
{
    int row = blockIdx.x;
    float M = Ms[row];
    float inv = 1.0f / Ss[row];
    float4* p = (float4*)(out + (long)row * VOCAB);
    for (int c = threadIdx.x; c < VOCAB / 4; c += 256) {
        float4 v = p[c];
        v.x = __expf(v.x - M) * inv;
        v.y = __expf(v.y - M) * inv;
        v.z = __expf(v.z - M) * inv;
        v.w = __expf(v.w - M) * inv;
        p[c] = v;
    }
}

// ---- K5: deterministic KL final reduce ------------------------------------
__global__ __launch_bounds__(256) void k5_kl_reduce(
    const float* __restrict__ blksum, float* __restrict__ kl_out)
{
    __shared__ float sred[256];
    float s = 0.0f;
    for (int i = threadIdx.x; i < NROWS; i += 256) s += blksum[i];
    sred[threadIdx.x] = s;
    __syncthreads();
    for (int st = 128; st > 0; st >>= 1) {
        if (threadIdx.x < st) sred[threadIdx.x] += sred[threadIdx.x + st];
        __syncthreads();
    }
    if (threadIdx.x == 0) kl_out[0] = 0.5f * sred[0];
}

extern "C" void kernel_launch(void* const* d_in, const int* in_sizes, int n_in,
                              void* d_out, int out_size, void* d_ws, size_t ws_size,
                              hipStream_t stream) {
    const float* mu  = (const float*)d_in[0];
    const float* ls  = (const float*)d_in[1];
    const float* eps = (const float*)d_in[2];
    const float* W   = (const float*)d_in[3];
    float* out = (float*)d_out;
    char* ws = (char*)d_ws;

    __bf16* Wp = (__bf16*)(ws + WP_OFF);
    __bf16* Ap = (__bf16*)(ws + AP_OFF);
    float* pm  = (float*)(ws + PM_OFF);
    float* ps  = (float*)(ws + PS_OFF);
    float* Ms  = (float*)(ws + MS_OFF);
    float* Ss  = (float*)(ws + SS_OFF);
    float* bs  = (float*)(ws + BS_OFF);
    float* kl  = out + 125000000L;

    // zero the padded rows of A' (2500..2559) and W' (50000..50047)
    hipMemsetAsync(ws + AP_OFF + (long)NROWS * KS * 2, 0, (long)(MPAD - NROWS) * KS * 2, stream);
    hipMemsetAsync(ws + WP_OFF + (long)VOCAB * KS * 2, 0, (long)(NTN * BN - VOCAB) * KS * 2, stream);

    k1_alphas_kl<<<NROWS, 256, 0, stream>>>(mu, ls, eps, Ap, bs);
    k1b_wsplit<<<VOCAB, 256, 0, stream>>>(W, Wp);
    k2_gemm<<<dim3(MPAD / BM, NTN), 256, 0, stream>>>(Ap, Wp, out, pm, ps);
    k3_rowstats<<<(NROWS + 255) / 256, 256, 0, stream>>>(pm, ps, Ms, Ss);
    k4_scale<<<NROWS, 256, 0, stream>>>(out, Ms, Ss);
    k5_kl_reduce<<<1, 256, 0, stream>>>(bs, kl);
}

// Round 3
// 490.807 us; speedup vs baseline: 1.8072x; 1.8072x over previous
//
#include <hip/hip_runtime.h>
#include <stdint.h>

// ---------------------------------------------------------------------------
// D-ETM decoder: alphas = mu + eps*exp(0.5*ls); KL; beta = softmax(alphas@W^T)
// out = [beta (125M f32), kl (1 f32)]
//
// R3 strategy:
//  - Pure bf16 GEMM, K=256 (global threshold 6.585e6 => bf16 error trivial)
//  - bf16 logits for row r live in the SECOND HALF of row r's own f32 span:
//    bytes [200000r+100000, 200000(r+1)). K4 reads them chunk-by-chunk with
//    read -> barrier -> write, so the only aliasing is intra-block and always
//    read-before-clobber. No cross-block races (R2's NaN bug).
//  - T2 swizzle: Ap/Wp stored pre-swizzled (unit u -> u^(row&7) within each
//    64-elem K-chunk); global_load_lds dest stays linear; ds_read applies XOR.
//
// ws layout (~35 MB):
//   Wp [50048][256] bf16  off 0
//   Ap [2560][256]  bf16  off 25,624,576
//   pm [391][2560]  f32   off 26,935,296
//   ps [391][2560]  f32   off 30,939,136
//   bs [2500]       f32   off 34,942,976
// ---------------------------------------------------------------------------

typedef __bf16 bf16x8 __attribute__((ext_vector_type(8)));
typedef float f32x4 __attribute__((ext_vector_type(4)));

#define TT 50
#define KTOP 50
#define RHO 256
#define VOCAB 50000
#define NROWS 2500
#define MPAD 2560
#define BM 128
#define BN 128
#define BKS 64
#define NTN 391   // ceil(50000/128)
#define LOG_DELTA (-5.29831736f)
#define ROWBYTES 200000L   // one beta row in f32 bytes

#define WP_OFF 0L
#define AP_OFF 25624576L
#define PM_OFF 26935296L
#define PS_OFF 30939136L
#define BS_OFF 34942976L

#define AS1(p) ((__attribute__((address_space(1))) void*)(uintptr_t)(p))
#define AS3(p) ((__attribute__((address_space(3))) void*)(p))

__device__ __forceinline__ int swz_idx(int r, int row) {
    // permute within each 64-elem chunk: 8-elem unit u -> u ^ (row&7)
    return (r & ~63) | (((((r >> 3) & 7) ^ (row & 7)) << 3)) | (r & 7);
}

// ---- K1: alphas, bf16 A' (swizzled), KL per-block partial sums ------------
__global__ __launch_bounds__(256) void k1_alphas_kl(
    const float* __restrict__ mu, const float* __restrict__ ls,
    const float* __restrict__ eps, __bf16* __restrict__ Ap,
    float* __restrict__ blksum)
{
    int b = blockIdx.x;          // row = t*50 + k, 0..2499
    int r = threadIdx.x;         // 0..255
    int t = b / KTOP;
    int k = b - t * KTOP;
    long iMu = ((long)k * TT + t) * RHO + r;     // mu_q_alpha[k][t][r]
    long iEp = ((long)t * KTOP + k) * RHO + r;   // eps[t][k][r]
    float m = mu[iMu], l = ls[iMu], e = eps[iEp];
    float alpha = fmaf(e, __expf(0.5f * l), m);

    Ap[(long)b * RHO + swz_idx(r, b)] = (__bf16)alpha;

    // KL term (t==0 prior N(0,1); t>0 prior N(alphas[t-1], delta))
    float p_mu = 0.0f, p_ls = 0.0f, denom = 1.0f + 1e-6f;
    if (t > 0) {
        float m0 = mu[iMu - RHO];
        float l0 = ls[iMu - RHO];
        float e0 = eps[iEp - (long)KTOP * RHO];
        p_mu = fmaf(e0, __expf(0.5f * l0), m0);
        p_ls = LOG_DELTA;
        denom = 0.005f + 1e-6f;
    }
    float sq = __expf(l);
    float d = m - p_mu;
    float term = (sq + d * d) / denom - 1.0f + p_ls - l;

    __shared__ float sred[256];
    sred[r] = term;
    __syncthreads();
    for (int s = 128; s > 0; s >>= 1) {
        if (r < s) sred[r] += sred[r + s];
        __syncthreads();
    }
    if (r == 0) blksum[b] = sred[0];
}

// ---- K1b: W bf16 (swizzled) -----------------------------------------------
__global__ __launch_bounds__(256) void k1b_wsplit(
    const float* __restrict__ W, __bf16* __restrict__ Wp)
{
    long v = blockIdx.x;         // 0..49999
    int r = threadIdx.x;
    float w = W[v * RHO + r];
    Wp[v * RHO + swz_idx(r, (int)v)] = (__bf16)w;
}

// ---- K2: bf16 MFMA GEMM (M=2560, N=50048, K=256) + bf16 logits + partials -
__global__ __launch_bounds__(256) void k2_gemm(
    const __bf16* __restrict__ Ap, const __bf16* __restrict__ Wp,
    char* __restrict__ outbase, float* __restrict__ pm, float* __restrict__ ps)
{
    __shared__ alignas(16) __bf16 As[BM * BKS];
    __shared__ alignas(16) __bf16 Ws[BN * BKS];
    __shared__ float red_m[2][BM];
    __shared__ float red_s[2][BM];

    const int tid = threadIdx.x;
    const int wave = tid >> 6;
    const int lane = tid & 63;
    const int tm = blockIdx.x;   // 0..19
    const int tn = blockIdx.y;   // 0..390
    const int wr = wave >> 1;
    const int wc = wave & 1;
    const int lhi = lane >> 4;
    const int llo = lane & 15;

    f32x4 acc[4][4];
#pragma unroll
    for (int m = 0; m < 4; ++m)
#pragma unroll
        for (int n = 0; n < 4; ++n)
#pragma unroll
            for (int i = 0; i < 4; ++i) acc[m][n][i] = 0.0f;

    const long arow0 = (long)tm * BM;
    const long wrow0 = (long)tn * BN;

    for (int kt = 0; kt < RHO / BKS; ++kt) {
#pragma unroll
        for (int i = 0; i < 4; ++i) {
            int seg = wave * 4 + i;                 // 0..15
            int row = seg * 8 + (lane >> 3);        // 0..127
            int col = (lane & 7) * 8;
            const __bf16* srcA = Ap + (arow0 + row) * RHO + kt * BKS + col;
            __builtin_amdgcn_global_load_lds(AS1(srcA), AS3(&As[seg * 8 * BKS]), 16, 0, 0);
            const __bf16* srcW = Wp + (wrow0 + row) * RHO + kt * BKS + col;
            __builtin_amdgcn_global_load_lds(AS1(srcW), AS3(&Ws[seg * 8 * BKS]), 16, 0, 0);
        }
        __syncthreads();
#pragma unroll
        for (int kk = 0; kk < BKS / 32; ++kk) {
            bf16x8 af[4], bfr[4];
#pragma unroll
            for (int m = 0; m < 4; ++m) {
                int r = wr * 64 + m * 16 + llo;
                af[m] = *(const bf16x8*)&As[r * BKS + ((((kk << 2) + lhi) ^ (r & 7)) << 3)];
            }
#pragma unroll
            for (int n = 0; n < 4; ++n) {
                int r = wc * 64 + n * 16 + llo;
                bfr[n] = *(const bf16x8*)&Ws[r * BKS + ((((kk << 2) + lhi) ^ (r & 7)) << 3)];
            }
#pragma unroll
            for (int m = 0; m < 4; ++m)
#pragma unroll
                for (int n = 0; n < 4; ++n)
                    acc[m][n] = __builtin_amdgcn_mfma_f32_16x16x32_bf16(
                        af[m], bfr[n], acc[m][n], 0, 0, 0);
        }
        __syncthreads();
    }

    // ---- epilogue: bf16 logits (into row's own second half) + partials ----
    float lf[4][4][4];
#pragma unroll
    for (int m = 0; m < 4; ++m) {
#pragma unroll
        for (int i = 0; i < 4; ++i) {
            long rg = arow0 + wr * 64 + m * 16 + lhi * 4 + i;
            if (rg < NROWS) {
                __bf16* lrow = (__bf16*)(outbase + rg * ROWBYTES + 100000);
#pragma unroll
                for (int n = 0; n < 4; ++n) {
                    int cg = tn * BN + wc * 64 + n * 16 + llo;
                    __bf16 lb = (__bf16)acc[m][n][i];
                    lf[m][n][i] = (float)lb;
                    if (cg < VOCAB) lrow[cg] = lb;
                }
            } else {
#pragma unroll
                for (int n = 0; n < 4; ++n) lf[m][n][i] = 0.0f;
            }
        }
    }

#pragma unroll
    for (int m = 0; m < 4; ++m) {
#pragma unroll
        for (int i = 0; i < 4; ++i) {
            float mx = -1e30f;
#pragma unroll
            for (int n = 0; n < 4; ++n) {
                int cg = tn * BN + wc * 64 + n * 16 + llo;
                if (cg < VOCAB) mx = fmaxf(mx, lf[m][n][i]);
            }
#pragma unroll
            for (int dm = 1; dm < 16; dm <<= 1) mx = fmaxf(mx, __shfl_xor(mx, dm));
            float sm = 0.0f;
#pragma unroll
            for (int n = 0; n < 4; ++n) {
                int cg = tn * BN + wc * 64 + n * 16 + llo;
                if (cg < VOCAB) sm += __expf(lf[m][n][i] - mx);
            }
#pragma unroll
            for (int dm = 1; dm < 16; dm <<= 1) sm += __shfl_xor(sm, dm);
            if (llo == 0) {
                int rl = wr * 64 + m * 16 + lhi * 4 + i;
                red_m[wc][rl] = mx;
                red_s[wc][rl] = sm;
            }
        }
    }
    __syncthreads();
    if (tid < BM) {
        float m0 = red_m[0][tid], m1 = red_m[1][tid];
        float M = fmaxf(m0, m1);
        float S = red_s[0][tid] * __expf(m0 - M) + red_s[1][tid] * __expf(m1 - M);
        long idx = (long)tn * MPAD + tm * BM + tid;
        pm[idx] = M;
        ps[idx] = S;
    }
}

// ---- K4: per-row stats combine + beta = exp(l - M)/S ----------------------
__global__ __launch_bounds__(256) void k4_stats_beta(
    const float* __restrict__ pm, const float* __restrict__ ps,
    char* __restrict__ outbase)
{
    int row = blockIdx.x;
    int t = threadIdx.x;

    // combine 391 per-tile partials -> (M, S)
    float m_loc = -1e30f, s_loc = 0.0f;
    for (int j = t; j < NTN; j += 256) {
        float mj = pm[(long)j * MPAD + row];
        float sj = ps[(long)j * MPAD + row];
        if (mj > m_loc) { s_loc = s_loc * __expf(m_loc - mj) + sj; m_loc = mj; }
        else            { s_loc += sj * __expf(mj - m_loc); }
    }
    __shared__ float sm_m[256];
    __shared__ float sm_s[256];
    sm_m[t] = m_loc; sm_s[t] = s_loc;
    __syncthreads();
    for (int st = 128; st > 0; st >>= 1) {
        if (t < st) {
            float m1 = sm_m[t], s1 = sm_s[t];
            float m2 = sm_m[t + st], s2 = sm_s[t + st];
            float M = fmaxf(m1, m2);
            sm_m[t] = M;
            sm_s[t] = s1 * __expf(m1 - M) + s2 * __expf(m2 - M);
        }
        __syncthreads();
    }
    float M = sm_m[0];
    float invS = 1.0f / sm_s[0];

    // beta: read bf16 chunk -> barrier -> write f32. bf16 logits live in
    // THIS row's second half, so clobbering is intra-block only; chunk j0's
    // f32 writes clobber bf16 cols < 2*j0-45904 <= cols already read.
    const __bf16* lrow = (const __bf16*)(outbase + (long)row * ROWBYTES + 100000);
    float* orow = (float*)(outbase + (long)row * ROWBYTES);
    for (int c0 = 0; c0 < VOCAB; c0 += 2048) {
        int j = c0 + t * 8;
        bool act = (j + 8 <= VOCAB);
        uint4 u4;
        if (act) u4 = *(const uint4*)(lrow + j);
        __syncthreads();
        if (act) {
            uint32_t w[4] = {u4.x, u4.y, u4.z, u4.w};
            float f[8];
#pragma unroll
            for (int e = 0; e < 4; ++e) {
                f[2 * e]     = __uint_as_float(w[e] << 16);
                f[2 * e + 1] = __uint_as_float(w[e] & 0xFFFF0000u);
            }
#pragma unroll
            for (int e = 0; e < 8; ++e) f[e] = __expf(f[e] - M) * invS;
            *(float4*)(orow + j)     = make_float4(f[0], f[1], f[2], f[3]);
            *(float4*)(orow + j + 4) = make_float4(f[4], f[5], f[6], f[7]);
        }
    }
}

// ---- K5: deterministic KL final reduce ------------------------------------
__global__ __launch_bounds__(256) void k5_kl_reduce(
    const float* __restrict__ blksum, float* __restrict__ kl_out)
{
    __shared__ float sred[256];
    float s = 0.0f;
    for (int i = threadIdx.x; i < NROWS; i += 256) s += blksum[i];
    sred[threadIdx.x] = s;
    __syncthreads();
    for (int st = 128; st > 0; st >>= 1) {
        if (threadIdx.x < st) sred[threadIdx.x] += sred[threadIdx.x + st];
        __syncthreads();
    }
    if (threadIdx.x == 0) kl_out[0] = 0.5f * sred[0];
}

extern "C" void kernel_launch(void* const* d_in, const int* in_sizes, int n_in,
                              void* d_out, int out_size, void* d_ws, size_t ws_size,
                              hipStream_t stream) {
    const float* mu  = (const float*)d_in[0];
    const float* ls  = (const float*)d_in[1];
    const float* eps = (const float*)d_in[2];
    const float* W   = (const float*)d_in[3];
    char* outbase = (char*)d_out;
    char* ws = (char*)d_ws;

    __bf16* Wp = (__bf16*)(ws + WP_OFF);
    __bf16* Ap = (__bf16*)(ws + AP_OFF);
    float* pm  = (float*)(ws + PM_OFF);
    float* ps  = (float*)(ws + PS_OFF);
    float* bs  = (float*)(ws + BS_OFF);
    float* kl  = (float*)d_out + 125000000L;

    // zero the padded rows of A' (2500..2559) and W' (50000..50047)
    hipMemsetAsync(ws + AP_OFF + (long)NROWS * RHO * 2, 0, (long)(MPAD - NROWS) * RHO * 2, stream);
    hipMemsetAsync(ws + WP_OFF + (long)VOCAB * RHO * 2, 0, (long)(NTN * BN - VOCAB) * RHO * 2, stream);

    k1_alphas_kl<<<NROWS, 256, 0, stream>>>(mu, ls, eps, Ap, bs);
    k1b_wsplit<<<VOCAB, 256, 0, stream>>>(W, Wp);
    k2_gemm<<<dim3(MPAD / BM, NTN), 256, 0, stream>>>(Ap, Wp, outbase, pm, ps);
    k4_stats_beta<<<NROWS, 256, 0, stream>>>(pm, ps, outbase);
    k5_kl_reduce<<<1, 256, 0, stream>>>(bs, kl);
}

// Round 4
// 472.375 us; speedup vs baseline: 1.8777x; 1.0390x over previous
//
#include <hip/hip_runtime.h>
#include <stdint.h>

// ---------------------------------------------------------------------------
// D-ETM decoder: alphas = mu + eps*exp(0.5*ls); KL; beta = softmax(alphas@W^T)
// out = [beta (125M f32), kl (1 f32)]
//
// R4:
//  - K2 -> 256x256 tile, 8 waves, BK=64, double-buffered LDS, prefetch overlap
//  - bijective XCD swizzle over the 1960-block grid (1960 = 8*245)
//  - no in-launch memsets: K1/K1b write the pad rows
//  - bf16 logits in row's own second half of d_out (R3 scheme, race-free)
//  - Ap/Wp pre-swizzled (unit u -> u^(row&7) per 64-elem chunk), linear
//    global_load_lds dest, XOR on ds_read
//
// ws layout (~31 MB):
//   Wp [50176][256] bf16  off 0
//   Ap [2560][256]  bf16  off 25,690,112
//   pm [196][2560]  f32   off 27,000,832
//   ps [196][2560]  f32   off 29,007,872
//   bs [2500]       f32   off 31,014,912
// ---------------------------------------------------------------------------

typedef __bf16 bf16x8 __attribute__((ext_vector_type(8)));
typedef float f32x4 __attribute__((ext_vector_type(4)));

#define TT 50
#define KTOP 50
#define RHO 256
#define VOCAB 50000
#define NROWS 2500
#define MPAD 2560
#define BM 256
#define BN 256
#define BK 64
#define NTN 196          // ceil(50000/256)
#define NTM 10
#define NPADV (NTN * BN) // 50176
#define LOG_DELTA (-5.29831736f)
#define ROWBYTES 200000L

#define WP_OFF 0L
#define AP_OFF 25690112L
#define PM_OFF 27000832L
#define PS_OFF 29007872L
#define BS_OFF 31014912L

#define AS1(p) ((__attribute__((address_space(1))) void*)(uintptr_t)(p))
#define AS3(p) ((__attribute__((address_space(3))) void*)(p))

__device__ __forceinline__ int swz_idx(int r, int row) {
    return (r & ~63) | (((((r >> 3) & 7) ^ (row & 7)) << 3)) | (r & 7);
}

// ---- K1: alphas -> bf16 A' (swizzled, incl. zero pad rows), KL partials ---
__global__ __launch_bounds__(256) void k1_alphas_kl(
    const float* __restrict__ mu, const float* __restrict__ ls,
    const float* __restrict__ eps, __bf16* __restrict__ Ap,
    float* __restrict__ blksum)
{
    int b = blockIdx.x;          // 0..2559 (rows >= 2500 are pad)
    int r = threadIdx.x;
    if (b >= NROWS) { Ap[(long)b * RHO + r] = (__bf16)0.0f; return; }
    int t = b / KTOP;
    int k = b - t * KTOP;
    long iMu = ((long)k * TT + t) * RHO + r;
    long iEp = ((long)t * KTOP + k) * RHO + r;
    float m = mu[iMu], l = ls[iMu], e = eps[iEp];
    float alpha = fmaf(e, __expf(0.5f * l), m);

    Ap[(long)b * RHO + swz_idx(r, b)] = (__bf16)alpha;

    float p_mu = 0.0f, p_ls = 0.0f, denom = 1.0f + 1e-6f;
    if (t > 0) {
        float m0 = mu[iMu - RHO];
        float l0 = ls[iMu - RHO];
        float e0 = eps[iEp - (long)KTOP * RHO];
        p_mu = fmaf(e0, __expf(0.5f * l0), m0);
        p_ls = LOG_DELTA;
        denom = 0.005f + 1e-6f;
    }
    float sq = __expf(l);
    float d = m - p_mu;
    float term = (sq + d * d) / denom - 1.0f + p_ls - l;

    __shared__ float sred[256];
    sred[r] = term;
    __syncthreads();
    for (int s = 128; s > 0; s >>= 1) {
        if (r < s) sred[r] += sred[r + s];
        __syncthreads();
    }
    if (r == 0) blksum[b] = sred[0];
}

// ---- K1b: W -> bf16 (swizzled, incl. zero pad rows) -----------------------
__global__ __launch_bounds__(256) void k1b_wsplit(
    const float* __restrict__ W, __bf16* __restrict__ Wp)
{
    long v = blockIdx.x;         // 0..50175
    int r = threadIdx.x;
    if (v >= VOCAB) { Wp[v * RHO + r] = (__bf16)0.0f; return; }
    float w = W[v * RHO + r];
    Wp[v * RHO + swz_idx(r, (int)v)] = (__bf16)w;
}

// ---- K2: 256x256 bf16 MFMA GEMM + bf16 logits + softmax partials ----------
__global__ __launch_bounds__(512, 2) void k2_gemm(
    const __bf16* __restrict__ Ap, const __bf16* __restrict__ Wp,
    char* __restrict__ outbase, float* __restrict__ pm, float* __restrict__ ps)
{
    __shared__ alignas(16) __bf16 As[2][BM * BK];   // 2 x 32 KB
    __shared__ alignas(16) __bf16 Ws[2][BN * BK];   // 2 x 32 KB
    __shared__ float red_m[4][BM];
    __shared__ float red_s[4][BM];

    const int tid = threadIdx.x;
    const int wave = tid >> 6;
    const int lane = tid & 63;
    // bijective XCD-chunked swizzle: 1960 = 8 * 245
    const int bid = blockIdx.x;
    const int orig = (bid & 7) * 245 + (bid >> 3);
    const int tm = orig % NTM;
    const int tn = orig / NTM;
    const int wr = wave >> 2;    // 0..1 : 128-row half
    const int wc = wave & 3;     // 0..3 : 64-col quarter
    const int lhi = lane >> 4;
    const int llo = lane & 15;
    const int lrow8 = lane >> 3;
    const int lcol8 = (lane & 7) * 8;

    f32x4 acc[8][4];
#pragma unroll
    for (int m = 0; m < 8; ++m)
#pragma unroll
        for (int n = 0; n < 4; ++n)
#pragma unroll
            for (int i = 0; i < 4; ++i) acc[m][n][i] = 0.0f;

    const long arow0 = (long)tm * BM;
    const long wrow0 = (long)tn * BN;

#define STAGE(buf, kt)                                                         \
    {                                                                          \
        _Pragma("unroll")                                                      \
        for (int i = 0; i < 4; ++i) {                                          \
            int seg = wave * 4 + i;               /* 0..31 */                  \
            int row = seg * 8 + lrow8;                                         \
            const __bf16* sA = Ap + (arow0 + row) * RHO + (kt) * BK + lcol8;   \
            __builtin_amdgcn_global_load_lds(AS1(sA), AS3(&As[buf][seg * 8 * BK]), 16, 0, 0); \
            const __bf16* sW = Wp + (wrow0 + row) * RHO + (kt) * BK + lcol8;   \
            __builtin_amdgcn_global_load_lds(AS1(sW), AS3(&Ws[buf][seg * 8 * BK]), 16, 0, 0); \
        }                                                                      \
    }

#define COMPUTE(buf)                                                           \
    {                                                                          \
        _Pragma("unroll")                                                      \
        for (int kk = 0; kk < 2; ++kk) {                                       \
            bf16x8 af[8], bfr[4];                                              \
            _Pragma("unroll")                                                  \
            for (int m = 0; m < 8; ++m) {                                      \
                int r = wr * 128 + m * 16 + llo;                               \
                af[m] = *(const bf16x8*)&As[buf][r * BK + ((((kk << 2) + lhi) ^ (r & 7)) << 3)]; \
            }                                                                  \
            _Pragma("unroll")                                                  \
            for (int n = 0; n < 4; ++n) {                                      \
                int r = wc * 64 + n * 16 + llo;                                \
                bfr[n] = *(const bf16x8*)&Ws[buf][r * BK + ((((kk << 2) + lhi) ^ (r & 7)) << 3)]; \
            }                                                                  \
            _Pragma("unroll")                                                  \
            for (int m = 0; m < 8; ++m)                                        \
                _Pragma("unroll")                                              \
                for (int n = 0; n < 4; ++n)                                    \
                    acc[m][n] = __builtin_amdgcn_mfma_f32_16x16x32_bf16(       \
                        af[m], bfr[n], acc[m][n], 0, 0, 0);                    \
        }                                                                      \
    }

    STAGE(0, 0);
    __syncthreads();
#pragma unroll
    for (int kt = 0; kt < 4; ++kt) {
        if (kt < 3) STAGE((kt + 1) & 1, kt + 1);
        COMPUTE(kt & 1);
        __syncthreads();
    }
#undef STAGE
#undef COMPUTE

    // ---- epilogue: round to bf16 in place, store logits -------------------
#pragma unroll
    for (int m = 0; m < 8; ++m) {
#pragma unroll
        for (int i = 0; i < 4; ++i) {
            long rg = arow0 + wr * 128 + m * 16 + lhi * 4 + i;
            if (rg < NROWS) {
                __bf16* lr = (__bf16*)(outbase + rg * ROWBYTES + 100000);
#pragma unroll
                for (int n = 0; n < 4; ++n) {
                    int cg = tn * BN + wc * 64 + n * 16 + llo;
                    __bf16 lb = (__bf16)acc[m][n][i];
                    acc[m][n][i] = (float)lb;
                    if (cg < VOCAB) lr[cg] = lb;
                }
            } else {
#pragma unroll
                for (int n = 0; n < 4; ++n) acc[m][n][i] = 0.0f;
            }
        }
    }

    // ---- per-row (max, sumexp) partials over this wave's 64 cols ----------
#pragma unroll
    for (int m = 0; m < 8; ++m) {
#pragma unroll
        for (int i = 0; i < 4; ++i) {
            float mx = -1e30f;
#pragma unroll
            for (int n = 0; n < 4; ++n) {
                int cg = tn * BN + wc * 64 + n * 16 + llo;
                if (cg < VOCAB) mx = fmaxf(mx, acc[m][n][i]);
            }
#pragma unroll
            for (int dm = 1; dm < 16; dm <<= 1) mx = fmaxf(mx, __shfl_xor(mx, dm));
            float sm = 0.0f;
#pragma unroll
            for (int n = 0; n < 4; ++n) {
                int cg = tn * BN + wc * 64 + n * 16 + llo;
                if (cg < VOCAB) sm += __expf(acc[m][n][i] - mx);
            }
#pragma unroll
            for (int dm = 1; dm < 16; dm <<= 1) sm += __shfl_xor(sm, dm);
            if (llo == 0) {
                int rl = wr * 128 + m * 16 + lhi * 4 + i;
                red_m[wc][rl] = mx;
                red_s[wc][rl] = sm;
            }
        }
    }
    __syncthreads();
    if (tid < BM) {
        float M = red_m[0][tid];
#pragma unroll
        for (int w = 1; w < 4; ++w) M = fmaxf(M, red_m[w][tid]);
        float S = 0.0f;
#pragma unroll
        for (int w = 0; w < 4; ++w) S += red_s[w][tid] * __expf(red_m[w][tid] - M);
        long idx = (long)tn * MPAD + tm * BM + tid;
        pm[idx] = M;
        ps[idx] = S;
    }
}

// ---- K4: per-row stats combine + beta = exp(l - M)/S ----------------------
__global__ __launch_bounds__(256) void k4_stats_beta(
    const float* __restrict__ pm, const float* __restrict__ ps,
    char* __restrict__ outbase)
{
    int row = blockIdx.x;
    int t = threadIdx.x;

    float m_loc = -1e30f, s_loc = 0.0f;
    for (int j = t; j < NTN; j += 256) {
        float mj = pm[(long)j * MPAD + row];
        float sj = ps[(long)j * MPAD + row];
        if (mj > m_loc) { s_loc = s_loc * __expf(m_loc - mj) + sj; m_loc = mj; }
        else            { s_loc += sj * __expf(mj - m_loc); }
    }
    __shared__ float sm_m[256];
    __shared__ float sm_s[256];
    sm_m[t] = m_loc; sm_s[t] = s_loc;
    __syncthreads();
    for (int st = 128; st > 0; st >>= 1) {
        if (t < st) {
            float m1 = sm_m[t], s1 = sm_s[t];
            float m2 = sm_m[t + st], s2 = sm_s[t + st];
            float M = fmaxf(m1, m2);
            sm_m[t] = M;
            sm_s[t] = s1 * __expf(m1 - M) + s2 * __expf(m2 - M);
        }
        __syncthreads();
    }
    float M = sm_m[0];
    float invS = 1.0f / sm_s[0];

    // read bf16 chunk -> barrier -> write f32 (intra-row aliasing only)
    const __bf16* lr = (const __bf16*)(outbase + (long)row * ROWBYTES + 100000);
    float* orow = (float*)(outbase + (long)row * ROWBYTES);
    for (int c0 = 0; c0 < VOCAB; c0 += 2048) {
        int j = c0 + t * 8;
        bool act = (j + 8 <= VOCAB);
        uint4 u4;
        if (act) u4 = *(const uint4*)(lr + j);
        __syncthreads();
        if (act) {
            uint32_t w[4] = {u4.x, u4.y, u4.z, u4.w};
            float f[8];
#pragma unroll
            for (int e = 0; e < 4; ++e) {
                f[2 * e]     = __uint_as_float(w[e] << 16);
                f[2 * e + 1] = __uint_as_float(w[e] & 0xFFFF0000u);
            }
#pragma unroll
            for (int e = 0; e < 8; ++e) f[e] = __expf(f[e] - M) * invS;
            *(float4*)(orow + j)     = make_float4(f[0], f[1], f[2], f[3]);
            *(float4*)(orow + j + 4) = make_float4(f[4], f[5], f[6], f[7]);
        }
    }
}

// ---- K5: deterministic KL final reduce ------------------------------------
__global__ __launch_bounds__(256) void k5_kl_reduce(
    const float* __restrict__ blksum, float* __restrict__ kl_out)
{
    __shared__ float sred[256];
    float s = 0.0f;
    for (int i = threadIdx.x; i < NROWS; i += 256) s += blksum[i];
    sred[threadIdx.x] = s;
    __syncthreads();
    for (int st = 128; st > 0; st >>= 1) {
        if (threadIdx.x < st) sred[threadIdx.x] += sred[threadIdx.x + st];
        __syncthreads();
    }
    if (threadIdx.x == 0) kl_out[0] = 0.5f * sred[0];
}

extern "C" void kernel_launch(void* const* d_in, const int* in_sizes, int n_in,
                              void* d_out, int out_size, void* d_ws, size_t ws_size,
                              hipStream_t stream) {
    const float* mu  = (const float*)d_in[0];
    const float* ls  = (const float*)d_in[1];
    const float* eps = (const float*)d_in[2];
    const float* W   = (const float*)d_in[3];
    char* outbase = (char*)d_out;
    char* ws = (char*)d_ws;

    __bf16* Wp = (__bf16*)(ws + WP_OFF);
    __bf16* Ap = (__bf16*)(ws + AP_OFF);
    float* pm  = (float*)(ws + PM_OFF);
    float* ps  = (float*)(ws + PS_OFF);
    float* bs  = (float*)(ws + BS_OFF);
    float* kl  = (float*)d_out + 125000000L;

    k1_alphas_kl<<<MPAD, 256, 0, stream>>>(mu, ls, eps, Ap, bs);
    k1b_wsplit<<<NPADV, 256, 0, stream>>>(W, Wp);
    k2_gemm<<<NTM * NTN, 512, 0, stream>>>(Ap, Wp, outbase, pm, ps);
    k4_stats_beta<<<NROWS, 256, 0, stream>>>(pm, ps, outbase);
    k5_kl_reduce<<<1, 256, 0, stream>>>(bs, kl);
}

// Round 5
// 466.042 us; speedup vs baseline: 1.9033x; 1.0136x over previous
//
#include <hip/hip_runtime.h>
#include <stdint.h>

// ---------------------------------------------------------------------------
// D-ETM decoder: alphas = mu + eps*exp(0.5*ls); KL; beta = softmax(alphas@W^T)
// out = [beta (125M f32), kl (1 f32)]
//
// R5:
//  - K2 K-loop: counted-vmcnt pipeline (T4). Raw s_barrier + s_waitcnt
//    vmcnt(8) so the double-buffer prefetch survives the barrier (plain
//    __syncthreads drains vmcnt(0) -> serial stage/compute, the R4 failure).
//  - 256x256 tile, 8 waves, BK=64, dbuf LDS (128KB+8KB, 1 block/CU)
//  - bijective XCD swizzle (1960 = 8*245)
//  - bf16 logits in row's own second half of d_out (race-free, R3 scheme)
//  - Ap/Wp pre-swizzled (unit u -> u^(row&7) per 64-elem chunk), linear
//    global_load_lds dest, XOR on ds_read
//
// ws layout (~31 MB):
//   Wp [50176][256] bf16  off 0
//   Ap [2560][256]  bf16  off 25,690,112
//   pm [196][2560]  f32   off 27,000,832
//   ps [196][2560]  f32   off 29,007,872
//   bs [2500]       f32   off 31,014,912
// ---------------------------------------------------------------------------

typedef __bf16 bf16x8 __attribute__((ext_vector_type(8)));
typedef float f32x4 __attribute__((ext_vector_type(4)));

#define TT 50
#define KTOP 50
#define RHO 256
#define VOCAB 50000
#define NROWS 2500
#define MPAD 2560
#define BM 256
#define BN 256
#define BK 64
#define NTN 196          // ceil(50000/256)
#define NTM 10
#define NPADV (NTN * BN) // 50176
#define LOG_DELTA (-5.29831736f)
#define ROWBYTES 200000L

#define WP_OFF 0L
#define AP_OFF 25690112L
#define PM_OFF 27000832L
#define PS_OFF 29007872L
#define BS_OFF 31014912L

#define AS1(p) ((__attribute__((address_space(1))) void*)(uintptr_t)(p))
#define AS3(p) ((__attribute__((address_space(3))) void*)(p))

__device__ __forceinline__ int swz_idx(int r, int row) {
    return (r & ~63) | (((((r >> 3) & 7) ^ (row & 7)) << 3)) | (r & 7);
}

// ---- K1: alphas -> bf16 A' (swizzled, incl. zero pad rows), KL partials ---
__global__ __launch_bounds__(256) void k1_alphas_kl(
    const float* __restrict__ mu, const float* __restrict__ ls,
    const float* __restrict__ eps, __bf16* __restrict__ Ap,
    float* __restrict__ blksum)
{
    int b = blockIdx.x;          // 0..2559 (rows >= 2500 are pad)
    int r = threadIdx.x;
    if (b >= NROWS) { Ap[(long)b * RHO + r] = (__bf16)0.0f; return; }
    int t = b / KTOP;
    int k = b - t * KTOP;
    long iMu = ((long)k * TT + t) * RHO + r;
    long iEp = ((long)t * KTOP + k) * RHO + r;
    float m = mu[iMu], l = ls[iMu], e = eps[iEp];
    float alpha = fmaf(e, __expf(0.5f * l), m);

    Ap[(long)b * RHO + swz_idx(r, b)] = (__bf16)alpha;

    float p_mu = 0.0f, p_ls = 0.0f, denom = 1.0f + 1e-6f;
    if (t > 0) {
        float m0 = mu[iMu - RHO];
        float l0 = ls[iMu - RHO];
        float e0 = eps[iEp - (long)KTOP * RHO];
        p_mu = fmaf(e0, __expf(0.5f * l0), m0);
        p_ls = LOG_DELTA;
        denom = 0.005f + 1e-6f;
    }
    float sq = __expf(l);
    float d = m - p_mu;
    float term = (sq + d * d) / denom - 1.0f + p_ls - l;

    __shared__ float sred[256];
    sred[r] = term;
    __syncthreads();
    for (int s = 128; s > 0; s >>= 1) {
        if (r < s) sred[r] += sred[r + s];
        __syncthreads();
    }
    if (r == 0) blksum[b] = sred[0];
}

// ---- K1b: W -> bf16 (swizzled, incl. zero pad rows) -----------------------
__global__ __launch_bounds__(256) void k1b_wsplit(
    const float* __restrict__ W, __bf16* __restrict__ Wp)
{
    long v = blockIdx.x;         // 0..50175
    int r = threadIdx.x;
    if (v >= VOCAB) { Wp[v * RHO + r] = (__bf16)0.0f; return; }
    float w = W[v * RHO + r];
    Wp[v * RHO + swz_idx(r, (int)v)] = (__bf16)w;
}

// ---- K2: 256x256 bf16 MFMA GEMM + bf16 logits + softmax partials ----------
__global__ __launch_bounds__(512, 2) void k2_gemm(
    const __bf16* __restrict__ Ap, const __bf16* __restrict__ Wp,
    char* __restrict__ outbase, float* __restrict__ pm, float* __restrict__ ps)
{
    __shared__ alignas(16) __bf16 As[2][BM * BK];   // 2 x 32 KB
    __shared__ alignas(16) __bf16 Ws[2][BN * BK];   // 2 x 32 KB
    __shared__ float red_m[4][BM];
    __shared__ float red_s[4][BM];

    const int tid = threadIdx.x;
    const int wave = tid >> 6;
    const int lane = tid & 63;
    // bijective XCD-chunked swizzle: 1960 = 8 * 245
    const int bid = blockIdx.x;
    const int orig = (bid & 7) * 245 + (bid >> 3);
    const int tm = orig % NTM;
    const int tn = orig / NTM;
    const int wr = wave >> 2;    // 0..1 : 128-row half
    const int wc = wave & 3;     // 0..3 : 64-col quarter
    const int lhi = lane >> 4;
    const int llo = lane & 15;
    const int lrow8 = lane >> 3;
    const int lcol8 = (lane & 7) * 8;

    f32x4 acc[8][4];
#pragma unroll
    for (int m = 0; m < 8; ++m)
#pragma unroll
        for (int n = 0; n < 4; ++n)
#pragma unroll
            for (int i = 0; i < 4; ++i) acc[m][n][i] = 0.0f;

    const long arow0 = (long)tm * BM;
    const long wrow0 = (long)tn * BN;

#define STAGE(buf, kt)                                                         \
    {                                                                          \
        _Pragma("unroll")                                                      \
        for (int i = 0; i < 4; ++i) {                                          \
            int seg = wave * 4 + i;               /* 0..31 */                  \
            int row = seg * 8 + lrow8;                                         \
            const __bf16* sA = Ap + (arow0 + row) * RHO + (kt) * BK + lcol8;   \
            __builtin_amdgcn_global_load_lds(AS1(sA), AS3(&As[buf][seg * 8 * BK]), 16, 0, 0); \
            const __bf16* sW = Wp + (wrow0 + row) * RHO + (kt) * BK + lcol8;   \
            __builtin_amdgcn_global_load_lds(AS1(sW), AS3(&Ws[buf][seg * 8 * BK]), 16, 0, 0); \
        }                                                                      \
    }

#define COMPUTE(buf)                                                           \
    {                                                                          \
        _Pragma("unroll")                                                      \
        for (int kk = 0; kk < 2; ++kk) {                                       \
            bf16x8 af[8], bfr[4];                                              \
            _Pragma("unroll")                                                  \
            for (int m = 0; m < 8; ++m) {                                      \
                int r = wr * 128 + m * 16 + llo;                               \
                af[m] = *(const bf16x8*)&As[buf][r * BK + ((((kk << 2) + lhi) ^ (r & 7)) << 3)]; \
            }                                                                  \
            _Pragma("unroll")                                                  \
            for (int n = 0; n < 4; ++n) {                                      \
                int r = wc * 64 + n * 16 + llo;                                \
                bfr[n] = *(const bf16x8*)&Ws[buf][r * BK + ((((kk << 2) + lhi) ^ (r & 7)) << 3)]; \
            }                                                                  \
            _Pragma("unroll")                                                  \
            for (int m = 0; m < 8; ++m)                                        \
                _Pragma("unroll")                                              \
                for (int n = 0; n < 4; ++n)                                    \
                    acc[m][n] = __builtin_amdgcn_mfma_f32_16x16x32_bf16(       \
                        af[m], bfr[n], acc[m][n], 0, 0, 0);                    \
        }                                                                      \
    }

    // Counted-vmcnt pipeline: both buffers staged up front (16 loads/wave);
    // each iter waits only for the OLDEST 8 (current tile), computes, then
    // refills the freed buffer. Prefetch stays in flight across barriers.
    STAGE(0, 0);
    STAGE(1, 1);
#pragma unroll
    for (int kt = 0; kt < 4; ++kt) {
        if (kt < 3) {
            asm volatile("s_waitcnt vmcnt(8)\n\ts_barrier" ::: "memory");
        } else {
            asm volatile("s_waitcnt vmcnt(0)\n\ts_barrier" ::: "memory");
        }
        __builtin_amdgcn_sched_barrier(0);
        COMPUTE(kt & 1);
        asm volatile("s_barrier" ::: "memory");   // all waves done reading buf
        if (kt < 2) STAGE(kt & 1, kt + 2);
    }
#undef STAGE
#undef COMPUTE

    // ---- epilogue: round to bf16 in place, store logits -------------------
#pragma unroll
    for (int m = 0; m < 8; ++m) {
#pragma unroll
        for (int i = 0; i < 4; ++i) {
            long rg = arow0 + wr * 128 + m * 16 + lhi * 4 + i;
            if (rg < NROWS) {
                __bf16* lr = (__bf16*)(outbase + rg * ROWBYTES + 100000);
#pragma unroll
                for (int n = 0; n < 4; ++n) {
                    int cg = tn * BN + wc * 64 + n * 16 + llo;
                    __bf16 lb = (__bf16)acc[m][n][i];
                    acc[m][n][i] = (float)lb;
                    if (cg < VOCAB) lr[cg] = lb;
                }
            } else {
#pragma unroll
                for (int n = 0; n < 4; ++n) acc[m][n][i] = 0.0f;
            }
        }
    }

    // ---- per-row (max, sumexp) partials over this wave's 64 cols ----------
#pragma unroll
    for (int m = 0; m < 8; ++m) {
#pragma unroll
        for (int i = 0; i < 4; ++i) {
            float mx = -1e30f;
#pragma unroll
            for (int n = 0; n < 4; ++n) {
                int cg = tn * BN + wc * 64 + n * 16 + llo;
                if (cg < VOCAB) mx = fmaxf(mx, acc[m][n][i]);
            }
#pragma unroll
            for (int dm = 1; dm < 16; dm <<= 1) mx = fmaxf(mx, __shfl_xor(mx, dm));
            float sm = 0.0f;
#pragma unroll
            for (int n = 0; n < 4; ++n) {
                int cg = tn * BN + wc * 64 + n * 16 + llo;
                if (cg < VOCAB) sm += __expf(acc[m][n][i] - mx);
            }
#pragma unroll
            for (int dm = 1; dm < 16; dm <<= 1) sm += __shfl_xor(sm, dm);
            if (llo == 0) {
                int rl = wr * 128 + m * 16 + lhi * 4 + i;
                red_m[wc][rl] = mx;
                red_s[wc][rl] = sm;
            }
        }
    }
    __syncthreads();
    if (tid < BM) {
        float M = red_m[0][tid];
#pragma unroll
        for (int w = 1; w < 4; ++w) M = fmaxf(M, red_m[w][tid]);
        float S = 0.0f;
#pragma unroll
        for (int w = 0; w < 4; ++w) S += red_s[w][tid] * __expf(red_m[w][tid] - M);
        long idx = (long)tn * MPAD + tm * BM + tid;
        pm[idx] = M;
        ps[idx] = S;
    }
}

// ---- K4: per-row stats combine + beta = exp(l - M)/S ----------------------
__global__ __launch_bounds__(256) void k4_stats_beta(
    const float* __restrict__ pm, const float* __restrict__ ps,
    char* __restrict__ outbase)
{
    int row = blockIdx.x;
    int t = threadIdx.x;

    float m_loc = -1e30f, s_loc = 0.0f;
    for (int j = t; j < NTN; j += 256) {
        float mj = pm[(long)j * MPAD + row];
        float sj = ps[(long)j * MPAD + row];
        if (mj > m_loc) { s_loc = s_loc * __expf(m_loc - mj) + sj; m_loc = mj; }
        else            { s_loc += sj * __expf(mj - m_loc); }
    }
    __shared__ float sm_m[256];
    __shared__ float sm_s[256];
    sm_m[t] = m_loc; sm_s[t] = s_loc;
    __syncthreads();
    for (int st = 128; st > 0; st >>= 1) {
        if (t < st) {
            float m1 = sm_m[t], s1 = sm_s[t];
            float m2 = sm_m[t + st], s2 = sm_s[t + st];
            float M = fmaxf(m1, m2);
            sm_m[t] = M;
            sm_s[t] = s1 * __expf(m1 - M) + s2 * __expf(m2 - M);
        }
        __syncthreads();
    }
    float M = sm_m[0];
    float invS = 1.0f / sm_s[0];

    // read bf16 chunk -> barrier -> write f32 (intra-row aliasing only)
    const __bf16* lr = (const __bf16*)(outbase + (long)row * ROWBYTES + 100000);
    float* orow = (float*)(outbase + (long)row * ROWBYTES);
    for (int c0 = 0; c0 < VOCAB; c0 += 2048) {
        int j = c0 + t * 8;
        bool act = (j + 8 <= VOCAB);
        uint4 u4;
        if (act) u4 = *(const uint4*)(lr + j);
        __syncthreads();
        if (act) {
            uint32_t w[4] = {u4.x, u4.y, u4.z, u4.w};
            float f[8];
#pragma unroll
            for (int e = 0; e < 4; ++e) {
                f[2 * e]     = __uint_as_float(w[e] << 16);
                f[2 * e + 1] = __uint_as_float(w[e] & 0xFFFF0000u);
            }
#pragma unroll
            for (int e = 0; e < 8; ++e) f[e] = __expf(f[e] - M) * invS;
            *(float4*)(orow + j)     = make_float4(f[0], f[1], f[2], f[3]);
            *(float4*)(orow + j + 4) = make_float4(f[4], f[5], f[6], f[7]);
        }
    }
}

// ---- K5: deterministic KL final reduce ------------------------------------
__global__ __launch_bounds__(256) void k5_kl_reduce(
    const float* __restrict__ blksum, float* __restrict__ kl_out)
{
    __shared__ float sred[256];
    float s = 0.0f;
    for (int i = threadIdx.x; i < NROWS; i += 256) s += blksum[i];
    sred[threadIdx.x] = s;
    __syncthreads();
    for (int st = 128; st > 0; st >>= 1) {
        if (threadIdx.x < st) sred[threadIdx.x] += sred[threadIdx.x + st];
        __syncthreads();
    }
    if (threadIdx.x == 0) kl_out[0] = 0.5f * sred[0];
}

extern "C" void kernel_launch(void* const* d_in, const int* in_sizes, int n_in,
                              void* d_out, int out_size, void* d_ws, size_t ws_size,
                              hipStream_t stream) {
    const float* mu  = (const float*)d_in[0];
    const float* ls  = (const float*)d_in[1];
    const float* eps = (const float*)d_in[2];
    const float* W   = (const float*)d_in[3];
    char* outbase = (char*)d_out;
    char* ws = (char*)d_ws;

    __bf16* Wp = (__bf16*)(ws + WP_OFF);
    __bf16* Ap = (__bf16*)(ws + AP_OFF);
    float* pm  = (float*)(ws + PM_OFF);
    float* ps  = (float*)(ws + PS_OFF);
    float* bs  = (float*)(ws + BS_OFF);
    float* kl  = (float*)d_out + 125000000L;

    k1_alphas_kl<<<MPAD, 256, 0, stream>>>(mu, ls, eps, Ap, bs);
    k1b_wsplit<<<NPADV, 256, 0, stream>>>(W, Wp);
    k2_gemm<<<NTM * NTN, 512, 0, stream>>>(Ap, Wp, outbase, pm, ps);
    k4_stats_beta<<<NROWS, 256, 0, stream>>>(pm, ps, outbase);
    k5_kl_reduce<<<1, 256, 0, stream>>>(bs, kl);
}

// Round 6
// 453.417 us; speedup vs baseline: 1.9563x; 1.0278x over previous
//
#include <hip/hip_runtime.h>
#include <stdint.h>

// ---------------------------------------------------------------------------
// D-ETM decoder: alphas = mu + eps*exp(0.5*ls); KL; beta = softmax(alphas@W^T)
// out = [beta (125M f32), kl (1 f32)]
//
// R6:
//  - K2 epilogue: round acc->bf16 into a 256x264 LDS tile (unioned over the
//    dead As/Ws buffers), then coalesced b128 stores (512 B contiguous per
//    row) instead of 128 scattered 2-B stores per thread (the R1-R5 sink).
//  - K-loop: counted-vmcnt double-buffer pipeline (kept from R5).
//  - bijective XCD swizzle (1960 = 8*245); bf16 logits in row's own second
//    half of d_out (race-free); Ap/Wp pre-swizzled, XOR on ds_read.
//
// ws layout (~31 MB): Wp[50176][256] bf16 @0; Ap[2560][256] bf16 @25,690,112;
//   pm[196][2560] f32 @27,000,832; ps @29,007,872; bs[2500] f32 @31,014,912
// ---------------------------------------------------------------------------

typedef __bf16 bf16x8 __attribute__((ext_vector_type(8)));
typedef float f32x4 __attribute__((ext_vector_type(4)));

#define TT 50
#define KTOP 50
#define RHO 256
#define VOCAB 50000
#define NROWS 2500
#define MPAD 2560
#define BM 256
#define BN 256
#define BK 64
#define NTN 196          // ceil(50000/256)
#define NTM 10
#define NPADV (NTN * BN) // 50176
#define LOG_DELTA (-5.29831736f)
#define ROWBYTES 200000L
#define TSTRIDE 264      // bf16 elems per tile row (528 B, 16B-aligned)

#define WP_OFF 0L
#define AP_OFF 25690112L
#define PM_OFF 27000832L
#define PS_OFF 29007872L
#define BS_OFF 31014912L

#define AS1(p) ((__attribute__((address_space(1))) void*)(uintptr_t)(p))
#define AS3(p) ((__attribute__((address_space(3))) void*)(p))

__device__ __forceinline__ int swz_idx(int r, int row) {
    return (r & ~63) | (((((r >> 3) & 7) ^ (row & 7)) << 3)) | (r & 7);
}

// ---- K1: alphas -> bf16 A' (swizzled, incl. zero pad rows), KL partials ---
__global__ __launch_bounds__(256) void k1_alphas_kl(
    const float* __restrict__ mu, const float* __restrict__ ls,
    const float* __restrict__ eps, __bf16* __restrict__ Ap,
    float* __restrict__ blksum)
{
    int b = blockIdx.x;          // 0..2559 (rows >= 2500 are pad)
    int r = threadIdx.x;
    if (b >= NROWS) { Ap[(long)b * RHO + r] = (__bf16)0.0f; return; }
    int t = b / KTOP;
    int k = b - t * KTOP;
    long iMu = ((long)k * TT + t) * RHO + r;
    long iEp = ((long)t * KTOP + k) * RHO + r;
    float m = mu[iMu], l = ls[iMu], e = eps[iEp];
    float alpha = fmaf(e, __expf(0.5f * l), m);

    Ap[(long)b * RHO + swz_idx(r, b)] = (__bf16)alpha;

    float p_mu = 0.0f, p_ls = 0.0f, denom = 1.0f + 1e-6f;
    if (t > 0) {
        float m0 = mu[iMu - RHO];
        float l0 = ls[iMu - RHO];
        float e0 = eps[iEp - (long)KTOP * RHO];
        p_mu = fmaf(e0, __expf(0.5f * l0), m0);
        p_ls = LOG_DELTA;
        denom = 0.005f + 1e-6f;
    }
    float sq = __expf(l);
    float d = m - p_mu;
    float term = (sq + d * d) / denom - 1.0f + p_ls - l;

    __shared__ float sred[256];
    sred[r] = term;
    __syncthreads();
    for (int s = 128; s > 0; s >>= 1) {
        if (r < s) sred[r] += sred[r + s];
        __syncthreads();
    }
    if (r == 0) blksum[b] = sred[0];
}

// ---- K1b: W -> bf16 (swizzled, incl. zero pad rows) -----------------------
__global__ __launch_bounds__(256) void k1b_wsplit(
    const float* __restrict__ W, __bf16* __restrict__ Wp)
{
    long v = blockIdx.x;         // 0..50175
    int r = threadIdx.x;
    if (v >= VOCAB) { Wp[v * RHO + r] = (__bf16)0.0f; return; }
    float w = W[v * RHO + r];
    Wp[v * RHO + swz_idx(r, (int)v)] = (__bf16)w;
}

// ---- K2: 256x256 bf16 MFMA GEMM + coalesced bf16 logits + partials --------
__global__ __launch_bounds__(512, 2) void k2_gemm(
    const __bf16* __restrict__ Ap, const __bf16* __restrict__ Wp,
    char* __restrict__ outbase, float* __restrict__ pm, float* __restrict__ ps)
{
    // LDS: K-loop buffers (4 x 32 KB) union'd with the 256x264 bf16 out-tile
    __shared__ alignas(16) char lds_raw[135168 + 8192];
    __bf16* As0 = (__bf16*)lds_raw;
    __bf16* As1 = (__bf16*)(lds_raw + 32768);
    __bf16* Ws0 = (__bf16*)(lds_raw + 65536);
    __bf16* Ws1 = (__bf16*)(lds_raw + 98304);
    __bf16* tile = (__bf16*)lds_raw;                 // [256][TSTRIDE]
    float* red_m = (float*)(lds_raw + 135168);       // [4][256]
    float* red_s = (float*)(lds_raw + 139264);       // [4][256]

    const int tid = threadIdx.x;
    const int wave = tid >> 6;
    const int lane = tid & 63;
    // bijective XCD-chunked swizzle: 1960 = 8 * 245
    const int bid = blockIdx.x;
    const int orig = (bid & 7) * 245 + (bid >> 3);
    const int tm = orig % NTM;
    const int tn = orig / NTM;
    const int wr = wave >> 2;    // 0..1 : 128-row half
    const int wc = wave & 3;     // 0..3 : 64-col quarter
    const int lhi = lane >> 4;
    const int llo = lane & 15;
    const int lrow8 = lane >> 3;
    const int lcol8 = (lane & 7) * 8;

    f32x4 acc[8][4];
#pragma unroll
    for (int m = 0; m < 8; ++m)
#pragma unroll
        for (int n = 0; n < 4; ++n)
#pragma unroll
            for (int i = 0; i < 4; ++i) acc[m][n][i] = 0.0f;

    const long arow0 = (long)tm * BM;
    const long wrow0 = (long)tn * BN;

#define STAGE(AB, WB, kt)                                                      \
    {                                                                          \
        _Pragma("unroll")                                                      \
        for (int i = 0; i < 4; ++i) {                                          \
            int seg = wave * 4 + i;               /* 0..31 */                  \
            int row = seg * 8 + lrow8;                                         \
            const __bf16* sA = Ap + (arow0 + row) * RHO + (kt) * BK + lcol8;   \
            __builtin_amdgcn_global_load_lds(AS1(sA), AS3(AB + seg * 8 * BK), 16, 0, 0); \
            const __bf16* sW = Wp + (wrow0 + row) * RHO + (kt) * BK + lcol8;   \
            __builtin_amdgcn_global_load_lds(AS1(sW), AS3(WB + seg * 8 * BK), 16, 0, 0); \
        }                                                                      \
    }

#define COMPUTE(AB, WB)                                                        \
    {                                                                          \
        _Pragma("unroll")                                                      \
        for (int kk = 0; kk < 2; ++kk) {                                       \
            bf16x8 af[8], bfr[4];                                              \
            _Pragma("unroll")                                                  \
            for (int m = 0; m < 8; ++m) {                                      \
                int r = wr * 128 + m * 16 + llo;                               \
                af[m] = *(const bf16x8*)&AB[r * BK + ((((kk << 2) + lhi) ^ (r & 7)) << 3)]; \
            }                                                                  \
            _Pragma("unroll")                                                  \
            for (int n = 0; n < 4; ++n) {                                      \
                int r = wc * 64 + n * 16 + llo;                                \
                bfr[n] = *(const bf16x8*)&WB[r * BK + ((((kk << 2) + lhi) ^ (r & 7)) << 3)]; \
            }                                                                  \
            _Pragma("unroll")                                                  \
            for (int m = 0; m < 8; ++m)                                        \
                _Pragma("unroll")                                              \
                for (int n = 0; n < 4; ++n)                                    \
                    acc[m][n] = __builtin_amdgcn_mfma_f32_16x16x32_bf16(       \
                        af[m], bfr[n], acc[m][n], 0, 0, 0);                    \
        }                                                                      \
    }

#define WAITBAR(N)                                                             \
    asm volatile("s_waitcnt vmcnt(" #N ")\n\ts_barrier" ::: "memory");         \
    __builtin_amdgcn_sched_barrier(0);

    // Counted-vmcnt pipeline: both buffers staged up front; each iter waits
    // only for the OLDEST 8 loads (current tile); prefetch crosses barriers.
    STAGE(As0, Ws0, 0);
    STAGE(As1, Ws1, 1);
    WAITBAR(8);
    COMPUTE(As0, Ws0);
    asm volatile("s_barrier" ::: "memory");
    STAGE(As0, Ws0, 2);
    WAITBAR(8);
    COMPUTE(As1, Ws1);
    asm volatile("s_barrier" ::: "memory");
    STAGE(As1, Ws1, 3);
    WAITBAR(8);
    COMPUTE(As0, Ws0);
    asm volatile("s_barrier" ::: "memory");
    WAITBAR(0);
    COMPUTE(As1, Ws1);
    asm volatile("s_barrier" ::: "memory");   // all ds_reads consumed; LDS free
#undef STAGE
#undef COMPUTE
#undef WAITBAR

    // ---- epilogue 1: round acc to bf16, write LDS out-tile ----------------
#pragma unroll
    for (int m = 0; m < 8; ++m) {
#pragma unroll
        for (int i = 0; i < 4; ++i) {
            int r = wr * 128 + m * 16 + lhi * 4 + i;
#pragma unroll
            for (int n = 0; n < 4; ++n) {
                int c = wc * 64 + n * 16 + llo;
                __bf16 lb = (__bf16)acc[m][n][i];
                acc[m][n][i] = (float)lb;
                tile[r * TSTRIDE + c] = lb;
            }
        }
    }

    // ---- epilogue 2: per-row (max, sumexp) partials from registers --------
#pragma unroll
    for (int m = 0; m < 8; ++m) {
#pragma unroll
        for (int i = 0; i < 4; ++i) {
            float mx = -1e30f;
#pragma unroll
            for (int n = 0; n < 4; ++n) {
                int cg = tn * BN + wc * 64 + n * 16 + llo;
                if (cg < VOCAB) mx = fmaxf(mx, acc[m][n][i]);
            }
#pragma unroll
            for (int dm = 1; dm < 16; dm <<= 1) mx = fmaxf(mx, __shfl_xor(mx, dm));
            float sm = 0.0f;
#pragma unroll
            for (int n = 0; n < 4; ++n) {
                int cg = tn * BN + wc * 64 + n * 16 + llo;
                if (cg < VOCAB) sm += __expf(acc[m][n][i] - mx);
            }
#pragma unroll
            for (int dm = 1; dm < 16; dm <<= 1) sm += __shfl_xor(sm, dm);
            if (llo == 0) {
                int rl = wr * 128 + m * 16 + lhi * 4 + i;
                red_m[wc * 256 + rl] = mx;
                red_s[wc * 256 + rl] = sm;
            }
        }
    }
    __syncthreads();

    // ---- epilogue 3a: combine wave partials -> pm/ps (coalesced) ----------
    if (tid < BM) {
        float M = red_m[tid];
#pragma unroll
        for (int w = 1; w < 4; ++w) M = fmaxf(M, red_m[w * 256 + tid]);
        float S = 0.0f;
#pragma unroll
        for (int w = 0; w < 4; ++w) S += red_s[w * 256 + tid] * __expf(red_m[w * 256 + tid] - M);
        long idx = (long)tn * MPAD + tm * BM + tid;
        pm[idx] = M;
        ps[idx] = S;
    }

    // ---- epilogue 3b: coalesced bf16 logit stores (512 B per row chunk) ---
    {
        const int trow = tid >> 5;   // 0..15
        const int tcol = tid & 31;   // 8-col chunk index
        const int cg0 = tn * BN + tcol * 8;
#pragma unroll
        for (int it = 0; it < 16; ++it) {
            int row = it * 16 + trow;
            long rg = arow0 + row;
            if (rg < NROWS && cg0 < VOCAB) {
                bf16x8 v = *(const bf16x8*)&tile[row * TSTRIDE + tcol * 8];
                *(bf16x8*)((__bf16*)(outbase + rg * ROWBYTES + 100000) + cg0) = v;
            }
        }
    }
}

// ---- K4: per-row stats combine + beta = exp(l - M)/S ----------------------
__global__ __launch_bounds__(256) void k4_stats_beta(
    const float* __restrict__ pm, const float* __restrict__ ps,
    char* __restrict__ outbase)
{
    int row = blockIdx.x;
    int t = threadIdx.x;

    float m_loc = -1e30f, s_loc = 0.0f;
    for (int j = t; j < NTN; j += 256) {
        float mj = pm[(long)j * MPAD + row];
        float sj = ps[(long)j * MPAD + row];
        if (mj > m_loc) { s_loc = s_loc * __expf(m_loc - mj) + sj; m_loc = mj; }
        else            { s_loc += sj * __expf(mj - m_loc); }
    }
    __shared__ float sm_m[256];
    __shared__ float sm_s[256];
    sm_m[t] = m_loc; sm_s[t] = s_loc;
    __syncthreads();
    for (int st = 128; st > 0; st >>= 1) {
        if (t < st) {
            float m1 = sm_m[t], s1 = sm_s[t];
            float m2 = sm_m[t + st], s2 = sm_s[t + st];
            float M = fmaxf(m1, m2);
            sm_m[t] = M;
            sm_s[t] = s1 * __expf(m1 - M) + s2 * __expf(m2 - M);
        }
        __syncthreads();
    }
    float M = sm_m[0];
    float invS = 1.0f / sm_s[0];

    // read bf16 chunk -> barrier -> write f32 (intra-row aliasing only)
    const __bf16* lr = (const __bf16*)(outbase + (long)row * ROWBYTES + 100000);
    float* orow = (float*)(outbase + (long)row * ROWBYTES);
    for (int c0 = 0; c0 < VOCAB; c0 += 2048) {
        int j = c0 + t * 8;
        bool act = (j + 8 <= VOCAB);
        uint4 u4;
        if (act) u4 = *(const uint4*)(lr + j);
        __syncthreads();
        if (act) {
            uint32_t w[4] = {u4.x, u4.y, u4.z, u4.w};
            float f[8];
#pragma unroll
            for (int e = 0; e < 4; ++e) {
                f[2 * e]     = __uint_as_float(w[e] << 16);
                f[2 * e + 1] = __uint_as_float(w[e] & 0xFFFF0000u);
            }
#pragma unroll
            for (int e = 0; e < 8; ++e) f[e] = __expf(f[e] - M) * invS;
            *(float4*)(orow + j)     = make_float4(f[0], f[1], f[2], f[3]);
            *(float4*)(orow + j + 4) = make_float4(f[4], f[5], f[6], f[7]);
        }
    }
}

// ---- K5: deterministic KL final reduce ------------------------------------
__global__ __launch_bounds__(256) void k5_kl_reduce(
    const float* __restrict__ blksum, float* __restrict__ kl_out)
{
    __shared__ float sred[256];
    float s = 0.0f;
    for (int i = threadIdx.x; i < NROWS; i += 256) s += blksum[i];
    sred[threadIdx.x] = s;
    __syncthreads();
    for (int st = 128; st > 0; st >>= 1) {
        if (threadIdx.x < st) sred[threadIdx.x] += sred[threadIdx.x + st];
        __syncthreads();
    }
    if (threadIdx.x == 0) kl_out[0] = 0.5f * sred[0];
}

extern "C" void kernel_launch(void* const* d_in, const int* in_sizes, int n_in,
                              void* d_out, int out_size, void* d_ws, size_t ws_size,
                              hipStream_t stream) {
    const float* mu  = (const float*)d_in[0];
    const float* ls  = (const float*)d_in[1];
    const float* eps = (const float*)d_in[2];
    const float* W   = (const float*)d_in[3];
    char* outbase = (char*)d_out;
    char* ws = (char*)d_ws;

    __bf16* Wp = (__bf16*)(ws + WP_OFF);
    __bf16* Ap = (__bf16*)(ws + AP_OFF);
    float* pm  = (float*)(ws + PM_OFF);
    float* ps  = (float*)(ws + PS_OFF);
    float* bs  = (float*)(ws + BS_OFF);
    float* kl  = (float*)d_out + 125000000L;

    k1_alphas_kl<<<MPAD, 256, 0, stream>>>(mu, ls, eps, Ap, bs);
    k1b_wsplit<<<NPADV, 256, 0, stream>>>(W, Wp);
    k2_gemm<<<NTM * NTN, 512, 0, stream>>>(Ap, Wp, outbase, pm, ps);
    k4_stats_beta<<<NROWS, 256, 0, stream>>>(pm, ps, outbase);
    k5_kl_reduce<<<1, 256, 0, stream>>>(bs, kl);
}

// Round 7
// 443.053 us; speedup vs baseline: 2.0020x; 1.0234x over previous
//
#include <hip/hip_runtime.h>
#include <stdint.h>

// ---------------------------------------------------------------------------
// D-ETM decoder: alphas = mu + eps*exp(0.5*ls); KL; beta = softmax(alphas@W^T)
// out = [beta (125M f32), kl (1 f32)]
//
// R7:
//  - bf16 logits now live in d_ws (poison fill showed ws ~= 2 GB). K4 becomes
//    a barrier-free streaming kernel (read bf16 -> write f32). Host falls
//    back to the R6 d_out-tail + aliasing-barrier K4 if ws is small.
//  - K1 and K1b merged into one kernel (one launch, concurrent fill).
//  - K2: 256x256 MFMA GEMM, counted-vmcnt dbuf pipeline, LDS out-tile for
//    coalesced logit stores, XCD-bijective swizzle (unchanged from R6).
//
// ws layout (scheme A, ws >= ~282 MB):
//   LG [2500][50000] bf16 @ 0  (stride 100000 B/row)
//   Wp [50176][256] bf16 @ 250,000,000
//   Ap [2560][256]  bf16 @ 275,690,112
//   pm [196][2560]  f32  @ 277,000,832
//   ps [196][2560]  f32  @ 279,007,872
//   bs [2500]       f32  @ 281,014,912
// ---------------------------------------------------------------------------

typedef __bf16 bf16x8 __attribute__((ext_vector_type(8)));
typedef float f32x4 __attribute__((ext_vector_type(4)));

#define TT 50
#define KTOP 50
#define RHO 256
#define VOCAB 50000
#define NROWS 2500
#define MPAD 2560
#define BM 256
#define BN 256
#define BK 64
#define NTN 196          // ceil(50000/256)
#define NTM 10
#define NPADV (NTN * BN) // 50176
#define LOG_DELTA (-5.29831736f)
#define ROWBYTES 200000L
#define TSTRIDE 264      // bf16 elems per tile row (528 B, 16B-aligned)

#define AS1(p) ((__attribute__((address_space(1))) void*)(uintptr_t)(p))
#define AS3(p) ((__attribute__((address_space(3))) void*)(p))

__device__ __forceinline__ int swz_idx(int r, int row) {
    return (r & ~63) | (((((r >> 3) & 7) ^ (row & 7)) << 3)) | (r & 7);
}

// ---- K1: merged alphas+KL (blocks 0..2559) and W split (blocks 2560+) -----
__global__ __launch_bounds__(256) void k1_prep(
    const float* __restrict__ mu, const float* __restrict__ ls,
    const float* __restrict__ eps, const float* __restrict__ W,
    __bf16* __restrict__ Ap, __bf16* __restrict__ Wp,
    float* __restrict__ blksum)
{
    int b = blockIdx.x;
    int r = threadIdx.x;
    if (b >= MPAD) {
        long v = b - MPAD;   // 0..50175
        if (v >= VOCAB) { Wp[v * RHO + r] = (__bf16)0.0f; return; }
        float w = W[v * RHO + r];
        Wp[v * RHO + swz_idx(r, (int)v)] = (__bf16)w;
        return;
    }
    if (b >= NROWS) { Ap[(long)b * RHO + r] = (__bf16)0.0f; return; }
    int t = b / KTOP;
    int k = b - t * KTOP;
    long iMu = ((long)k * TT + t) * RHO + r;
    long iEp = ((long)t * KTOP + k) * RHO + r;
    float m = mu[iMu], l = ls[iMu], e = eps[iEp];
    float alpha = fmaf(e, __expf(0.5f * l), m);

    Ap[(long)b * RHO + swz_idx(r, b)] = (__bf16)alpha;

    float p_mu = 0.0f, p_ls = 0.0f, denom = 1.0f + 1e-6f;
    if (t > 0) {
        float m0 = mu[iMu - RHO];
        float l0 = ls[iMu - RHO];
        float e0 = eps[iEp - (long)KTOP * RHO];
        p_mu = fmaf(e0, __expf(0.5f * l0), m0);
        p_ls = LOG_DELTA;
        denom = 0.005f + 1e-6f;
    }
    float sq = __expf(l);
    float d = m - p_mu;
    float term = (sq + d * d) / denom - 1.0f + p_ls - l;

    __shared__ float sred[256];
    sred[r] = term;
    __syncthreads();
    for (int s = 128; s > 0; s >>= 1) {
        if (r < s) sred[r] += sred[r + s];
        __syncthreads();
    }
    if (r == 0) blksum[b] = sred[0];
}

// ---- K2: 256x256 bf16 MFMA GEMM + coalesced bf16 logits + partials --------
__global__ __launch_bounds__(512, 2) void k2_gemm(
    const __bf16* __restrict__ Ap, const __bf16* __restrict__ Wp,
    char* __restrict__ lgbase, long lgstride,
    float* __restrict__ pm, float* __restrict__ ps)
{
    // LDS: K-loop buffers (4 x 32 KB) union'd with the 256x264 bf16 out-tile
    __shared__ alignas(16) char lds_raw[135168 + 8192];
    __bf16* As0 = (__bf16*)lds_raw;
    __bf16* As1 = (__bf16*)(lds_raw + 32768);
    __bf16* Ws0 = (__bf16*)(lds_raw + 65536);
    __bf16* Ws1 = (__bf16*)(lds_raw + 98304);
    __bf16* tile = (__bf16*)lds_raw;                 // [256][TSTRIDE]
    float* red_m = (float*)(lds_raw + 135168);       // [4][256]
    float* red_s = (float*)(lds_raw + 139264);       // [4][256]

    const int tid = threadIdx.x;
    const int wave = tid >> 6;
    const int lane = tid & 63;
    // bijective XCD-chunked swizzle: 1960 = 8 * 245
    const int bid = blockIdx.x;
    const int orig = (bid & 7) * 245 + (bid >> 3);
    const int tm = orig % NTM;
    const int tn = orig / NTM;
    const int wr = wave >> 2;    // 0..1 : 128-row half
    const int wc = wave & 3;     // 0..3 : 64-col quarter
    const int lhi = lane >> 4;
    const int llo = lane & 15;
    const int lrow8 = lane >> 3;
    const int lcol8 = (lane & 7) * 8;

    f32x4 acc[8][4];
#pragma unroll
    for (int m = 0; m < 8; ++m)
#pragma unroll
        for (int n = 0; n < 4; ++n)
#pragma unroll
            for (int i = 0; i < 4; ++i) acc[m][n][i] = 0.0f;

    const long arow0 = (long)tm * BM;
    const long wrow0 = (long)tn * BN;

#define STAGE(AB, WB, kt)                                                      \
    {                                                                          \
        _Pragma("unroll")                                                      \
        for (int i = 0; i < 4; ++i) {                                          \
            int seg = wave * 4 + i;               /* 0..31 */                  \
            int row = seg * 8 + lrow8;                                         \
            const __bf16* sA = Ap + (arow0 + row) * RHO + (kt) * BK + lcol8;   \
            __builtin_amdgcn_global_load_lds(AS1(sA), AS3(AB + seg * 8 * BK), 16, 0, 0); \
            const __bf16* sW = Wp + (wrow0 + row) * RHO + (kt) * BK + lcol8;   \
            __builtin_amdgcn_global_load_lds(AS1(sW), AS3(WB + seg * 8 * BK), 16, 0, 0); \
        }                                                                      \
    }

#define COMPUTE(AB, WB)                                                        \
    {                                                                          \
        _Pragma("unroll")                                                      \
        for (int kk = 0; kk < 2; ++kk) {                                       \
            bf16x8 af[8], bfr[4];                                              \
            _Pragma("unroll")                                                  \
            for (int m = 0; m < 8; ++m) {                                      \
                int r = wr * 128 + m * 16 + llo;                               \
                af[m] = *(const bf16x8*)&AB[r * BK + ((((kk << 2) + lhi) ^ (r & 7)) << 3)]; \
            }                                                                  \
            _Pragma("unroll")                                                  \
            for (int n = 0; n < 4; ++n) {                                      \
                int r = wc * 64 + n * 16 + llo;                                \
                bfr[n] = *(const bf16x8*)&WB[r * BK + ((((kk << 2) + lhi) ^ (r & 7)) << 3)]; \
            }                                                                  \
            _Pragma("unroll")                                                  \
            for (int m = 0; m < 8; ++m)                                        \
                _Pragma("unroll")                                              \
                for (int n = 0; n < 4; ++n)                                    \
                    acc[m][n] = __builtin_amdgcn_mfma_f32_16x16x32_bf16(       \
                        af[m], bfr[n], acc[m][n], 0, 0, 0);                    \
        }                                                                      \
    }

#define WAITBAR(N)                                                             \
    asm volatile("s_waitcnt vmcnt(" #N ")\n\ts_barrier" ::: "memory");         \
    __builtin_amdgcn_sched_barrier(0);

    STAGE(As0, Ws0, 0);
    STAGE(As1, Ws1, 1);
    WAITBAR(8);
    COMPUTE(As0, Ws0);
    asm volatile("s_barrier" ::: "memory");
    STAGE(As0, Ws0, 2);
    WAITBAR(8);
    COMPUTE(As1, Ws1);
    asm volatile("s_barrier" ::: "memory");
    STAGE(As1, Ws1, 3);
    WAITBAR(8);
    COMPUTE(As0, Ws0);
    asm volatile("s_barrier" ::: "memory");
    WAITBAR(0);
    COMPUTE(As1, Ws1);
    asm volatile("s_barrier" ::: "memory");   // all ds_reads consumed; LDS free
#undef STAGE
#undef COMPUTE
#undef WAITBAR

    // ---- epilogue 1: round acc to bf16, write LDS out-tile ----------------
#pragma unroll
    for (int m = 0; m < 8; ++m) {
#pragma unroll
        for (int i = 0; i < 4; ++i) {
            int r = wr * 128 + m * 16 + lhi * 4 + i;
#pragma unroll
            for (int n = 0; n < 4; ++n) {
                int c = wc * 64 + n * 16 + llo;
                __bf16 lb = (__bf16)acc[m][n][i];
                acc[m][n][i] = (float)lb;
                tile[r * TSTRIDE + c] = lb;
            }
        }
    }

    // ---- epilogue 2: per-row (max, sumexp) partials from registers --------
#pragma unroll
    for (int m = 0; m < 8; ++m) {
#pragma unroll
        for (int i = 0; i < 4; ++i) {
            float mx = -1e30f;
#pragma unroll
            for (int n = 0; n < 4; ++n) {
                int cg = tn * BN + wc * 64 + n * 16 + llo;
                if (cg < VOCAB) mx = fmaxf(mx, acc[m][n][i]);
            }
#pragma unroll
            for (int dm = 1; dm < 16; dm <<= 1) mx = fmaxf(mx, __shfl_xor(mx, dm));
            float sm = 0.0f;
#pragma unroll
            for (int n = 0; n < 4; ++n) {
                int cg = tn * BN + wc * 64 + n * 16 + llo;
                if (cg < VOCAB) sm += __expf(acc[m][n][i] - mx);
            }
#pragma unroll
            for (int dm = 1; dm < 16; dm <<= 1) sm += __shfl_xor(sm, dm);
            if (llo == 0) {
                int rl = wr * 128 + m * 16 + lhi * 4 + i;
                red_m[wc * 256 + rl] = mx;
                red_s[wc * 256 + rl] = sm;
            }
        }
    }
    __syncthreads();

    // ---- epilogue 3a: combine wave partials -> pm/ps (coalesced) ----------
    if (tid < BM) {
        float M = red_m[tid];
#pragma unroll
        for (int w = 1; w < 4; ++w) M = fmaxf(M, red_m[w * 256 + tid]);
        float S = 0.0f;
#pragma unroll
        for (int w = 0; w < 4; ++w) S += red_s[w * 256 + tid] * __expf(red_m[w * 256 + tid] - M);
        long idx = (long)tn * MPAD + tm * BM + tid;
        pm[idx] = M;
        ps[idx] = S;
    }

    // ---- epilogue 3b: coalesced bf16 logit stores (512 B per row chunk) ---
    {
        const int trow = tid >> 5;   // 0..15
        const int tcol = tid & 31;   // 8-col chunk index
        const int cg0 = tn * BN + tcol * 8;
#pragma unroll
        for (int it = 0; it < 16; ++it) {
            int row = it * 16 + trow;
            long rg = arow0 + row;
            if (rg < NROWS && cg0 < VOCAB) {
                bf16x8 v = *(const bf16x8*)&tile[row * TSTRIDE + tcol * 8];
                *(bf16x8*)(lgbase + rg * lgstride + cg0 * 2) = v;
            }
        }
    }
}

// ---- K4a: streaming (logits in ws, no aliasing, no barriers) --------------
__global__ __launch_bounds__(256) void k4_stream(
    const float* __restrict__ pm, const float* __restrict__ ps,
    const char* __restrict__ lgbase, long lgstride, float* __restrict__ out)
{
    int row = blockIdx.x;
    int t = threadIdx.x;

    float m_loc = -1e30f, s_loc = 0.0f;
    for (int j = t; j < NTN; j += 256) {
        float mj = pm[(long)j * MPAD + row];
        float sj = ps[(long)j * MPAD + row];
        if (mj > m_loc) { s_loc = s_loc * __expf(m_loc - mj) + sj; m_loc = mj; }
        else            { s_loc += sj * __expf(mj - m_loc); }
    }
    __shared__ float sm_m[256];
    __shared__ float sm_s[256];
    sm_m[t] = m_loc; sm_s[t] = s_loc;
    __syncthreads();
    for (int st = 128; st > 0; st >>= 1) {
        if (t < st) {
            float m1 = sm_m[t], s1 = sm_s[t];
            float m2 = sm_m[t + st], s2 = sm_s[t + st];
            float M = fmaxf(m1, m2);
            sm_m[t] = M;
            sm_s[t] = s1 * __expf(m1 - M) + s2 * __expf(m2 - M);
        }
        __syncthreads();
    }
    float M = sm_m[0];
    float invS = 1.0f / sm_s[0];

    const __bf16* lr = (const __bf16*)(lgbase + (long)row * lgstride);
    float* orow = out + (long)row * VOCAB;
#pragma unroll 2
    for (int j = t * 8; j + 8 <= VOCAB; j += 2048) {
        uint4 u4 = *(const uint4*)(lr + j);
        uint32_t w[4] = {u4.x, u4.y, u4.z, u4.w};
        float f[8];
#pragma unroll
        for (int e = 0; e < 4; ++e) {
            f[2 * e]     = __uint_as_float(w[e] << 16);
            f[2 * e + 1] = __uint_as_float(w[e] & 0xFFFF0000u);
        }
#pragma unroll
        for (int e = 0; e < 8; ++e) f[e] = __expf(f[e] - M) * invS;
        *(float4*)(orow + j)     = make_float4(f[0], f[1], f[2], f[3]);
        *(float4*)(orow + j + 4) = make_float4(f[4], f[5], f[6], f[7]);
    }
}

// ---- K4b: aliased fallback (logits in d_out tail; R6 scheme) --------------
__global__ __launch_bounds__(256) void k4_alias(
    const float* __restrict__ pm, const float* __restrict__ ps,
    char* __restrict__ outbase)
{
    int row = blockIdx.x;
    int t = threadIdx.x;

    float m_loc = -1e30f, s_loc = 0.0f;
    for (int j = t; j < NTN; j += 256) {
        float mj = pm[(long)j * MPAD + row];
        float sj = ps[(long)j * MPAD + row];
        if (mj > m_loc) { s_loc = s_loc * __expf(m_loc - mj) + sj; m_loc = mj; }
        else            { s_loc += sj * __expf(mj - m_loc); }
    }
    __shared__ float sm_m[256];
    __shared__ float sm_s[256];
    sm_m[t] = m_loc; sm_s[t] = s_loc;
    __syncthreads();
    for (int st = 128; st > 0; st >>= 1) {
        if (t < st) {
            float m1 = sm_m[t], s1 = sm_s[t];
            float m2 = sm_m[t + st], s2 = sm_s[t + st];
            float M = fmaxf(m1, m2);
            sm_m[t] = M;
            sm_s[t] = s1 * __expf(m1 - M) + s2 * __expf(m2 - M);
        }
        __syncthreads();
    }
    float M = sm_m[0];
    float invS = 1.0f / sm_s[0];

    const __bf16* lr = (const __bf16*)(outbase + (long)row * ROWBYTES + 100000);
    float* orow = (float*)(outbase + (long)row * ROWBYTES);
    for (int c0 = 0; c0 < VOCAB; c0 += 2048) {
        int j = c0 + t * 8;
        bool act = (j + 8 <= VOCAB);
        uint4 u4;
        if (act) u4 = *(const uint4*)(lr + j);
        __syncthreads();
        if (act) {
            uint32_t w[4] = {u4.x, u4.y, u4.z, u4.w};
            float f[8];
#pragma unroll
            for (int e = 0; e < 4; ++e) {
                f[2 * e]     = __uint_as_float(w[e] << 16);
                f[2 * e + 1] = __uint_as_float(w[e] & 0xFFFF0000u);
            }
#pragma unroll
            for (int e = 0; e < 8; ++e) f[e] = __expf(f[e] - M) * invS;
            *(float4*)(orow + j)     = make_float4(f[0], f[1], f[2], f[3]);
            *(float4*)(orow + j + 4) = make_float4(f[4], f[5], f[6], f[7]);
        }
    }
}

// ---- K5: deterministic KL final reduce ------------------------------------
__global__ __launch_bounds__(256) void k5_kl_reduce(
    const float* __restrict__ blksum, float* __restrict__ kl_out)
{
    __shared__ float sred[256];
    float s = 0.0f;
    for (int i = threadIdx.x; i < NROWS; i += 256) s += blksum[i];
    sred[threadIdx.x] = s;
    __syncthreads();
    for (int st = 128; st > 0; st >>= 1) {
        if (threadIdx.x < st) sred[threadIdx.x] += sred[threadIdx.x + st];
        __syncthreads();
    }
    if (threadIdx.x == 0) kl_out[0] = 0.5f * sred[0];
}

extern "C" void kernel_launch(void* const* d_in, const int* in_sizes, int n_in,
                              void* d_out, int out_size, void* d_ws, size_t ws_size,
                              hipStream_t stream) {
    const float* mu  = (const float*)d_in[0];
    const float* ls  = (const float*)d_in[1];
    const float* eps = (const float*)d_in[2];
    const float* W   = (const float*)d_in[3];
    char* outbase = (char*)d_out;
    char* ws = (char*)d_ws;

    const bool big = ws_size >= 281100000UL;   // LG + Wp + Ap + pm + ps + bs
    const long base = big ? 250000000L : 0L;

    __bf16* Wp = (__bf16*)(ws + base);
    __bf16* Ap = (__bf16*)(ws + base + 25690112L);
    float* pm  = (float*)(ws + base + 27000832L);
    float* ps  = (float*)(ws + base + 29007872L);
    float* bs  = (float*)(ws + base + 31014912L);
    float* kl  = (float*)d_out + 125000000L;

    char* lg   = big ? ws : (outbase + 100000L);
    long  lstr = big ? 100000L : ROWBYTES;

    k1_prep<<<MPAD + NPADV, 256, 0, stream>>>(mu, ls, eps, W, Ap, Wp, bs);
    k2_gemm<<<NTM * NTN, 512, 0, stream>>>(Ap, Wp, lg, lstr, pm, ps);
    if (big) {
        k4_stream<<<NROWS, 256, 0, stream>>>(pm, ps, lg, lstr, (float*)d_out);
    } else {
        k4_alias<<<NROWS, 256, 0, stream>>>(pm, ps, outbase);
    }
    k5_kl_reduce<<<1, 256, 0, stream>>>(bs, kl);
}

// Round 8
// 384.931 us; speedup vs baseline: 2.3043x; 1.1510x over previous
//
#include <hip/hip_runtime.h>
#include <stdint.h>

// ---------------------------------------------------------------------------
// D-ETM decoder: alphas = mu + eps*exp(0.5*ls); KL; beta = softmax(alphas@W^T)
// out = [beta (125M f32), kl (1 f32)]
//
// R8: recompute-GEMM two-pass; NO logit buffer.
//   k1_prep : alphas->Ap (bf16, swizzled), W->Wp, KL block sums
//   k2_pass1: 256x256 MFMA GEMM -> per-tile (max, sumexp) partials only
//   k3_stats: combine partials -> per-row (M, S); + deterministic kl reduce
//   k2_pass2: identical GEMM (bit-identical acc) -> beta = exp(acc-M)/S
//             written straight to d_out (64-B sector-aligned dword stores)
// Removes the 500 MB logit round-trip and its cross-XCD L2 writeback.
//
// ws layout (~31 MB): Wp[50176][256] bf16 @0; Ap[2560][256] @25,690,112;
//   pm[196][2560] f32 @27,000,832; ps @29,007,872; bs @31,014,912;
//   Ms @31,025,152; Ss @31,035,392
// ---------------------------------------------------------------------------

typedef __bf16 bf16x8 __attribute__((ext_vector_type(8)));
typedef float f32x4 __attribute__((ext_vector_type(4)));

#define TT 50
#define KTOP 50
#define RHO 256
#define VOCAB 50000
#define NROWS 2500
#define MPAD 2560
#define BM 256
#define BN 256
#define BK 64
#define NTN 196          // ceil(50000/256)
#define NTM 10
#define NPADV (NTN * BN) // 50176
#define LOG_DELTA (-5.29831736f)

#define AS1(p) ((__attribute__((address_space(1))) void*)(uintptr_t)(p))
#define AS3(p) ((__attribute__((address_space(3))) void*)(p))

__device__ __forceinline__ int swz_idx(int r, int row) {
    return (r & ~63) | (((((r >> 3) & 7) ^ (row & 7)) << 3)) | (r & 7);
}

// ---- K1: merged alphas+KL (blocks 0..2559) and W split (blocks 2560+) -----
__global__ __launch_bounds__(256) void k1_prep(
    const float* __restrict__ mu, const float* __restrict__ ls,
    const float* __restrict__ eps, const float* __restrict__ W,
    __bf16* __restrict__ Ap, __bf16* __restrict__ Wp,
    float* __restrict__ blksum)
{
    int b = blockIdx.x;
    int r = threadIdx.x;
    if (b >= MPAD) {
        long v = b - MPAD;   // 0..50175
        if (v >= VOCAB) { Wp[v * RHO + r] = (__bf16)0.0f; return; }
        float w = W[v * RHO + r];
        Wp[v * RHO + swz_idx(r, (int)v)] = (__bf16)w;
        return;
    }
    if (b >= NROWS) { Ap[(long)b * RHO + r] = (__bf16)0.0f; return; }
    int t = b / KTOP;
    int k = b - t * KTOP;
    long iMu = ((long)k * TT + t) * RHO + r;
    long iEp = ((long)t * KTOP + k) * RHO + r;
    float m = mu[iMu], l = ls[iMu], e = eps[iEp];
    float alpha = fmaf(e, __expf(0.5f * l), m);

    Ap[(long)b * RHO + swz_idx(r, b)] = (__bf16)alpha;

    float p_mu = 0.0f, p_ls = 0.0f, denom = 1.0f + 1e-6f;
    if (t > 0) {
        float m0 = mu[iMu - RHO];
        float l0 = ls[iMu - RHO];
        float e0 = eps[iEp - (long)KTOP * RHO];
        p_mu = fmaf(e0, __expf(0.5f * l0), m0);
        p_ls = LOG_DELTA;
        denom = 0.005f + 1e-6f;
    }
    float sq = __expf(l);
    float d = m - p_mu;
    float term = (sq + d * d) / denom - 1.0f + p_ls - l;

    __shared__ float sred[256];
    sred[r] = term;
    __syncthreads();
    for (int s = 128; s > 0; s >>= 1) {
        if (r < s) sred[r] += sred[r + s];
        __syncthreads();
    }
    if (r == 0) blksum[b] = sred[0];
}

// ---- shared GEMM machinery (identical in both passes) ---------------------
#define GEMM_PRELUDE(LDS_EXTRA)                                                \
    __shared__ alignas(16) char lds_raw[131072 + LDS_EXTRA];                   \
    __bf16* As0 = (__bf16*)lds_raw;                                            \
    __bf16* As1 = (__bf16*)(lds_raw + 32768);                                  \
    __bf16* Ws0 = (__bf16*)(lds_raw + 65536);                                  \
    __bf16* Ws1 = (__bf16*)(lds_raw + 98304);                                  \
    const int tid = threadIdx.x;                                               \
    const int wave = tid >> 6;                                                 \
    const int lane = tid & 63;                                                 \
    const int bid = blockIdx.x;                                                \
    const int orig = (bid & 7) * 245 + (bid >> 3);                             \
    const int tm = orig % NTM;                                                 \
    const int tn = orig / NTM;                                                 \
    const int wr = wave >> 2;                                                  \
    const int wc = wave & 3;                                                   \
    const int lhi = lane >> 4;                                                 \
    const int llo = lane & 15;                                                 \
    const int lrow8 = lane >> 3;                                               \
    const int lcol8 = (lane & 7) * 8;                                          \
    f32x4 acc[8][4];                                                           \
    _Pragma("unroll")                                                          \
    for (int m = 0; m < 8; ++m)                                                \
        _Pragma("unroll")                                                      \
        for (int n = 0; n < 4; ++n)                                            \
            _Pragma("unroll")                                                  \
            for (int i = 0; i < 4; ++i) acc[m][n][i] = 0.0f;                   \
    const long arow0 = (long)tm * BM;                                          \
    const long wrow0 = (long)tn * BN;

#define STAGE(AB, WB, kt)                                                      \
    {                                                                          \
        _Pragma("unroll")                                                      \
        for (int i = 0; i < 4; ++i) {                                          \
            int seg = wave * 4 + i;                                            \
            int row = seg * 8 + lrow8;                                         \
            const __bf16* sA = Ap + (arow0 + row) * RHO + (kt) * BK + lcol8;   \
            __builtin_amdgcn_global_load_lds(AS1(sA), AS3(AB + seg * 8 * BK), 16, 0, 0); \
            const __bf16* sW = Wp + (wrow0 + row) * RHO + (kt) * BK + lcol8;   \
            __builtin_amdgcn_global_load_lds(AS1(sW), AS3(WB + seg * 8 * BK), 16, 0, 0); \
        }                                                                      \
    }

#define COMPUTE(AB, WB)                                                        \
    {                                                                          \
        _Pragma("unroll")                                                      \
        for (int kk = 0; kk < 2; ++kk) {                                       \
            bf16x8 af[8], bfr[4];                                              \
            _Pragma("unroll")                                                  \
            for (int m = 0; m < 8; ++m) {                                      \
                int r = wr * 128 + m * 16 + llo;                               \
                af[m] = *(const bf16x8*)&AB[r * BK + ((((kk << 2) + lhi) ^ (r & 7)) << 3)]; \
            }                                                                  \
            _Pragma("unroll")                                                  \
            for (int n = 0; n < 4; ++n) {                                      \
                int r = wc * 64 + n * 16 + llo;                                \
                bfr[n] = *(const bf16x8*)&WB[r * BK + ((((kk << 2) + lhi) ^ (r & 7)) << 3)]; \
            }                                                                  \
            _Pragma("unroll")                                                  \
            for (int m = 0; m < 8; ++m)                                        \
                _Pragma("unroll")                                              \
                for (int n = 0; n < 4; ++n)                                    \
                    acc[m][n] = __builtin_amdgcn_mfma_f32_16x16x32_bf16(       \
                        af[m], bfr[n], acc[m][n], 0, 0, 0);                    \
        }                                                                      \
    }

#define KLOOP                                                                  \
    STAGE(As0, Ws0, 0);                                                        \
    STAGE(As1, Ws1, 1);                                                        \
    asm volatile("s_waitcnt vmcnt(8)\n\ts_barrier" ::: "memory");              \
    __builtin_amdgcn_sched_barrier(0);                                         \
    COMPUTE(As0, Ws0);                                                         \
    asm volatile("s_barrier" ::: "memory");                                    \
    STAGE(As0, Ws0, 2);                                                        \
    asm volatile("s_waitcnt vmcnt(8)\n\ts_barrier" ::: "memory");              \
    __builtin_amdgcn_sched_barrier(0);                                         \
    COMPUTE(As1, Ws1);                                                         \
    asm volatile("s_barrier" ::: "memory");                                    \
    STAGE(As1, Ws1, 3);                                                        \
    asm volatile("s_waitcnt vmcnt(8)\n\ts_barrier" ::: "memory");              \
    __builtin_amdgcn_sched_barrier(0);                                         \
    COMPUTE(As0, Ws0);                                                         \
    asm volatile("s_barrier" ::: "memory");                                    \
    asm volatile("s_waitcnt vmcnt(0)\n\ts_barrier" ::: "memory");              \
    __builtin_amdgcn_sched_barrier(0);                                         \
    COMPUTE(As1, Ws1);

// ---- K2 pass 1: GEMM -> per-tile (max, sumexp) partials -------------------
__global__ __launch_bounds__(512, 2) void k2_pass1(
    const __bf16* __restrict__ Ap, const __bf16* __restrict__ Wp,
    float* __restrict__ pm, float* __restrict__ ps)
{
    GEMM_PRELUDE(8192)
    float* red_m = (float*)(lds_raw + 131072);       // [4][256]
    float* red_s = (float*)(lds_raw + 135168);       // [4][256]
    KLOOP
    asm volatile("s_barrier" ::: "memory");

#pragma unroll
    for (int m = 0; m < 8; ++m) {
#pragma unroll
        for (int i = 0; i < 4; ++i) {
            float mx = -1e30f;
#pragma unroll
            for (int n = 0; n < 4; ++n) {
                int cg = tn * BN + wc * 64 + n * 16 + llo;
                if (cg < VOCAB) mx = fmaxf(mx, acc[m][n][i]);
            }
#pragma unroll
            for (int dm = 1; dm < 16; dm <<= 1) mx = fmaxf(mx, __shfl_xor(mx, dm));
            float sm = 0.0f;
#pragma unroll
            for (int n = 0; n < 4; ++n) {
                int cg = tn * BN + wc * 64 + n * 16 + llo;
                if (cg < VOCAB) sm += __expf(acc[m][n][i] - mx);
            }
#pragma unroll
            for (int dm = 1; dm < 16; dm <<= 1) sm += __shfl_xor(sm, dm);
            if (llo == 0) {
                int rl = wr * 128 + m * 16 + lhi * 4 + i;
                red_m[wc * 256 + rl] = mx;
                red_s[wc * 256 + rl] = sm;
            }
        }
    }
    __syncthreads();
    if (tid < BM) {
        float M = red_m[tid];
#pragma unroll
        for (int w = 1; w < 4; ++w) M = fmaxf(M, red_m[w * 256 + tid]);
        float S = 0.0f;
#pragma unroll
        for (int w = 0; w < 4; ++w) S += red_s[w * 256 + tid] * __expf(red_m[w * 256 + tid] - M);
        long idx = (long)tn * MPAD + tm * BM + tid;
        pm[idx] = M;
        ps[idx] = S;
    }
}

// ---- K3: per-row (M,S) from partials (blocks 0..9); kl reduce (block 10) --
__global__ __launch_bounds__(256) void k3_stats(
    const float* __restrict__ pm, const float* __restrict__ ps,
    const float* __restrict__ blksum,
    float* __restrict__ Ms, float* __restrict__ Ss, float* __restrict__ kl_out)
{
    if (blockIdx.x == 10) {
        __shared__ float sred[256];
        float s = 0.0f;
        for (int i = threadIdx.x; i < NROWS; i += 256) s += blksum[i];
        sred[threadIdx.x] = s;
        __syncthreads();
        for (int st = 128; st > 0; st >>= 1) {
            if (threadIdx.x < st) sred[threadIdx.x] += sred[threadIdx.x + st];
            __syncthreads();
        }
        if (threadIdx.x == 0) kl_out[0] = 0.5f * sred[0];
        return;
    }
    int row = blockIdx.x * 256 + threadIdx.x;
    if (row >= NROWS) return;
    float M = -1e30f;
    for (int j = 0; j < NTN; ++j) M = fmaxf(M, pm[(long)j * MPAD + row]);
    float S = 0.0f;
    for (int j = 0; j < NTN; ++j)
        S += ps[(long)j * MPAD + row] * __expf(pm[(long)j * MPAD + row] - M);
    Ms[row] = M;
    Ss[row] = S;
}

// ---- K2 pass 2: identical GEMM -> beta = exp(acc - M)/S -> d_out ----------
__global__ __launch_bounds__(512, 2) void k2_pass2(
    const __bf16* __restrict__ Ap, const __bf16* __restrict__ Wp,
    const float* __restrict__ Ms, const float* __restrict__ Ss,
    float* __restrict__ out)
{
    GEMM_PRELUDE(2048)
    float* ms_lds = (float*)(lds_raw + 131072);      // [256]
    float* ss_lds = (float*)(lds_raw + 132096);      // [256] (inverse S)
    KLOOP
    asm volatile("s_barrier" ::: "memory");

    if (tid < 256) {
        long rg = arow0 + tid;
        float Mv = 0.0f, Sv = 1.0f;
        if (rg < NROWS) { Mv = Ms[rg]; Sv = Ss[rg]; }
        ms_lds[tid] = Mv;
        ss_lds[tid] = 1.0f / Sv;
    }
    __syncthreads();

#pragma unroll
    for (int m = 0; m < 8; ++m) {
#pragma unroll
        for (int i = 0; i < 4; ++i) {
            int rl = wr * 128 + m * 16 + lhi * 4 + i;
            long rg = arow0 + rl;
            if (rg < NROWS) {
                float M = ms_lds[rl];
                float invS = ss_lds[rl];
                float* orow = out + rg * (long)VOCAB;
#pragma unroll
                for (int n = 0; n < 4; ++n) {
                    int cg = tn * BN + wc * 64 + n * 16 + llo;
                    if (cg < VOCAB) orow[cg] = __expf(acc[m][n][i] - M) * invS;
                }
            }
        }
    }
}

extern "C" void kernel_launch(void* const* d_in, const int* in_sizes, int n_in,
                              void* d_out, int out_size, void* d_ws, size_t ws_size,
                              hipStream_t stream) {
    const float* mu  = (const float*)d_in[0];
    const float* ls  = (const float*)d_in[1];
    const float* eps = (const float*)d_in[2];
    const float* W   = (const float*)d_in[3];
    char* ws = (char*)d_ws;

    __bf16* Wp = (__bf16*)(ws);
    __bf16* Ap = (__bf16*)(ws + 25690112L);
    float* pm  = (float*)(ws + 27000832L);
    float* ps  = (float*)(ws + 29007872L);
    float* bs  = (float*)(ws + 31014912L);
    float* Ms  = (float*)(ws + 31025152L);
    float* Ss  = (float*)(ws + 31035392L);
    float* kl  = (float*)d_out + 125000000L;

    k1_prep<<<MPAD + NPADV, 256, 0, stream>>>(mu, ls, eps, W, Ap, Wp, bs);
    k2_pass1<<<NTM * NTN, 512, 0, stream>>>(Ap, Wp, pm, ps);
    k3_stats<<<11, 256, 0, stream>>>(pm, ps, bs, Ms, Ss, kl);
    k2_pass2<<<NTM * NTN, 512, 0, stream>>>(Ap, Wp, Ms, Ss, (float*)d_out);
}